// Round 10
// baseline (3043.763 us; speedup 1.0000x reference)
//
#include <hip/hip_runtime.h>

#define NG 100000
#define EG 400000
#define ELG 1200000
#define NT 50000
#define ET 100000
#define ELGT 300000

#define GEG ((EG + 63) / 64)     // 6250
#define GET ((ET + 63) / 64)     // 1563
#define GNG ((NG + 63) / 64)     // 1563
#define GNT ((NT + 63) / 64)     // 782

// concatenated CSR segment space: [G_lg(EG) | G_dst(NG) | T_lg(ET) | T_dst(NT)]
#define SEG1 EG
#define SEG2 (EG + NG)
#define SEG3 (EG + NG + ET)
#define NSEG_ALL (EG + NG + ET + NT)
#define NE_ALL (ELG + EG + ELGT + ET)
// padded CSR upper bound: every segment rounded up to multiple of 4 (+ read-ahead pad)
#define NE_PAD (NE_ALL + 3 * NSEG_ALL + 64)

typedef unsigned short u16;
typedef unsigned int u32;
typedef __attribute__((ext_vector_type(8))) short bf16x8;
typedef __attribute__((ext_vector_type(4))) float f32x4;
typedef __attribute__((ext_vector_type(4))) u32 u32x4;

#define TILE_B 16384   // one 64-row x 128-col bf16 tile (row stride 256 B)

__device__ __forceinline__ float bflo(u32 p){ return __uint_as_float(p << 16); }
__device__ __forceinline__ float bfhi(u32 p){ return __uint_as_float(p & 0xffff0000u); }
__device__ __forceinline__ float bf2f(u16 h){ return __uint_as_float(((u32)h) << 16); }
__device__ __forceinline__ u16 f2bf(float f){
  u32 u = __float_as_uint(f);
  u32 r = u + 0x7fffu + ((u >> 16) & 1u);
  return (u16)(r >> 16);
}
__device__ __forceinline__ float sigm(float x){ return 1.0f / (1.0f + __expf(-x)); }
__device__ __forceinline__ float tanh_(float x){ return 2.0f / (1.0f + __expf(-2.0f * x)) - 1.0f; }
__device__ __forceinline__ float relu_(float x){ return x > 0.0f ? x : 0.0f; }
__device__ __forceinline__ void wfence(){ __builtin_amdgcn_wave_barrier(); }

// non-temporal 16B store (write-once streams)
__device__ __forceinline__ void stnt4(void* p, uint4 d){
  u32x4 v = {d.x, d.y, d.z, d.w};
  __builtin_nontemporal_store(v, (u32x4*)p);
}

// LDS tile byte swizzle (T2): row stride 256B, XOR row bits into byte bits 4-6
__device__ __forceinline__ int swz(int r, int c){ return r * 256 + (c ^ ((r & 7) << 4)); }

__device__ __forceinline__ uint2 pack4(const f32x4& a){
  uint2 o;
  o.x = (u32)f2bf(a[0]) | ((u32)f2bf(a[1]) << 16);
  o.y = (u32)f2bf(a[2]) | ((u32)f2bf(a[3]) << 16);
  return o;
}
__device__ __forceinline__ void unp4(uint2 u, float v[4]){
  v[0] = bflo(u.x); v[1] = bfhi(u.x); v[2] = bflo(u.y); v[3] = bfhi(u.y);
}
__device__ __forceinline__ uint2 pack4a(const float v[4]){
  uint2 o;
  o.x = (u32)f2bf(v[0]) | ((u32)f2bf(v[1]) << 16);
  o.y = (u32)f2bf(v[2]) | ((u32)f2bf(v[3]) << 16);
  return o;
}
__device__ __forceinline__ bf16x8 zfrag(){
  union { uint4 u; bf16x8 b; } c; c.u = make_uint4(0, 0, 0, 0); return c.b;
}
__device__ __forceinline__ bf16x8 as_frag(uint4 u){
  union { uint4 u; bf16x8 b; } c; c.u = u; return c.b;
}
__device__ __forceinline__ bf16x8 packfrag(const float v[8]){
  union { uint4 u; bf16x8 b; } c;
  c.u.x = f2bf(v[0]) | ((u32)f2bf(v[1]) << 16);
  c.u.y = f2bf(v[2]) | ((u32)f2bf(v[3]) << 16);
  c.u.z = f2bf(v[4]) | ((u32)f2bf(v[5]) << 16);
  c.u.w = f2bf(v[6]) | ((u32)f2bf(v[7]) << 16);
  return c.b;
}

// ---------------- dtype sniffer (bf16 vs f32 inputs) ----------------
__global__ void k_sniff(const u32* __restrict__ g, int* __restrict__ flag){
  __shared__ int sh[2];
  if (threadIdx.x < 2) sh[threadIdx.x] = 0;
  __syncthreads();
  int c0 = 0, c1 = 0;
  for (int i = 0; i < 16; i++){
    u32 w = g[threadIdx.x * 16 + i];
    u32 lo = w & 0xFFFFu;
    if (lo == 0u) c0++;
    else { u32 e = (lo >> 7) & 0xFFu; if (e >= 96u && e <= 144u) c1++; }
  }
  atomicAdd(&sh[0], c0); atomicAdd(&sh[1], c1);
  __syncthreads();
  if (threadIdx.x == 0) *flag = (sh[0] < 512 && sh[1] > 2048) ? 1 : 0;
}

// all 13 weights -> f32 mirror arena (one launch)
__global__ void k_cvt_all(const void* p0, const void* p1, const void* p2, const void* p3,
                          const void* p4, const void* p5, const void* p6, const void* p7,
                          const void* p8, const void* p9, const void* p10, const void* p11,
                          const void* p12, float* __restrict__ wm, const int* __restrict__ flagp){
  int i = blockIdx.x * 256 + threadIdx.x;
  if (i >= 188416) return;
  const int offs[14] = {0,8192,16384,32768,40960,57344,73728,90112,106496,122880,139264,155648,172032,188416};
  const void* ps[13] = {p0,p1,p2,p3,p4,p5,p6,p7,p8,p9,p10,p11,p12};
  int w = 0;
  while (i >= offs[w + 1]) w++;
  int li = i - offs[w];
  wm[i] = (*flagp) ? bf2f(((const u16*)ps[w])[li]) : ((const float*)ps[w])[li];
}

// all MFMA B-fragment tables (one launch, 46 ks-blocks)
__global__ void k_mkfrag_all(const float* __restrict__ wm, u16* __restrict__ frag){
  const int wmo[13] = {0,8192,16384,32768,40960,57344,73728,90112,106496,122880,139264,155648,172032};
  const int nks[13] = {2,2,4,2,4,4,4,4,4,4,4,4,4};
  int b = blockIdx.x;            // 0..45
  int wi = 0, ks = b;
  while (ks >= nks[wi]){ ks -= nks[wi]; wi++; }
  const float* W = wm + wmo[wi];
  int nt = threadIdx.x >> 6, lane = threadIdx.x & 63;
  int kr = ks * 32 + ((lane >> 4) << 3);
  int col = nt * 16 + (lane & 15);
  u16* o = frag + (size_t)b * 4096 + nt * 512 + lane * 8;
  #pragma unroll
  for (int j = 0; j < 8; j++) o[j] = f2bf(W[(size_t)(kr + j) * 128 + col]);
}

// identity-matrix B-fragment table (4 ks-blocks): mma(A, I) = A in C-layout
__global__ void k_mkident(u16* __restrict__ fI){
  int ks = blockIdx.x;
  int nt = threadIdx.x >> 6, lane = threadIdx.x & 63;
  int kr = ks * 32 + ((lane >> 4) << 3);
  int col = nt * 16 + (lane & 15);
  u16* o = fI + (size_t)ks * 4096 + nt * 512 + lane * 8;
  #pragma unroll
  for (int j = 0; j < 8; j++) o[j] = (kr + j == col) ? (u16)0x3F80 : (u16)0;
}

// ---------------- dual-dtype row access ----------------
__device__ __forceinline__ const void* rowdt(const void* mat, size_t row, int W, int bf){
  return bf ? (const void*)((const u16*)mat + row * (size_t)W)
            : (const void*)((const float*)mat + row * (size_t)W);
}
__device__ __forceinline__ void load8(const void* rowbase, int c8, int bf, float v[8]){
  if (bf){
    uint4 d = ((const uint4*)rowbase)[c8];
    v[0]=bflo(d.x); v[1]=bfhi(d.x); v[2]=bflo(d.y); v[3]=bfhi(d.y);
    v[4]=bflo(d.z); v[5]=bfhi(d.z); v[6]=bflo(d.w); v[7]=bfhi(d.w);
  } else {
    const float4* p = (const float4*)rowbase + (c8 << 1);
    float4 a = p[0], b = p[1];
    v[0]=a.x; v[1]=a.y; v[2]=a.z; v[3]=a.w; v[4]=b.x; v[5]=b.y; v[6]=b.z; v[7]=b.w;
  }
}

// ---------------- unified CSR build (padded to multiples of 4) ----------------
__global__ void k_hist_all(const int* __restrict__ Glgd, const int* __restrict__ Gd,
                           const int* __restrict__ Tlgd, const int* __restrict__ Td,
                           int* __restrict__ cnt){
  int e = blockIdx.x * 256 + threadIdx.x;
  if (e >= NE_ALL) return;
  int seg;
  if (e < ELG)                       seg = Glgd[e];
  else if (e < ELG + EG)             seg = SEG1 + Gd[e - ELG];
  else if (e < ELG + EG + ELGT)      seg = SEG2 + Tlgd[e - ELG - EG];
  else                               seg = SEG3 + Td[e - ELG - EG - ELGT];
  atomicAdd(&cnt[seg], 1);
}

__global__ void k_scan1(const int* __restrict__ cnt, int n, int* __restrict__ csum){
  int base = blockIdx.x * 4096, tid = threadIdx.x;
  int s = 0;
  for (int i = 0; i < 16; i++){
    int idx = base + i * 256 + tid;
    if (idx < n) s += (cnt[idx] + 3) & ~3;      // padded count
  }
  __shared__ int red[4];
  for (int off = 32; off; off >>= 1) s += __shfl_down(s, off, 64);
  if ((tid & 63) == 0) red[tid >> 6] = s;
  __syncthreads();
  if (tid == 0) csum[blockIdx.x] = red[0] + red[1] + red[2] + red[3];
}

__global__ void k_scan2(int* csum, int nch, int* rowptr, int n){
  if (threadIdx.x == 0){
    int run = 0;
    for (int c = 0; c < nch; c++){ int t = csum[c]; csum[c] = run; run += t; }
    rowptr[n] = run;
  }
}

__global__ void k_scan3(const int* __restrict__ cnt, int n, const int* __restrict__ csum,
                        int* __restrict__ rowptr){
  __shared__ int buf[4096];
  __shared__ int tsum[256];
  int base = blockIdx.x * 4096, tid = threadIdx.x;
  for (int i = 0; i < 16; i++){
    int idx = base + i * 256 + tid;
    buf[i * 256 + tid] = (idx < n) ? ((cnt[idx] + 3) & ~3) : 0;   // padded count
  }
  __syncthreads();
  int run = 0;
  for (int i = 0; i < 16; i++){ int v = buf[tid * 16 + i]; buf[tid * 16 + i] = run; run += v; }
  tsum[tid] = run;
  __syncthreads();
  for (int off = 1; off < 256; off <<= 1){
    int v = (tid >= off) ? tsum[tid - off] : 0;
    __syncthreads();
    tsum[tid] += v;
    __syncthreads();
  }
  int texcl = tsum[tid] - run;
  int cbase = csum[blockIdx.x];
  for (int i = 0; i < 16; i++){
    int idx = base + tid * 16 + i;
    if (idx < n) rowptr[idx] = cbase + texcl + buf[tid * 16 + i];
  }
}

__global__ void k_fill_all(const int* __restrict__ Glgd, const int* __restrict__ Glgs,
                           const int* __restrict__ Gd,
                           const int* __restrict__ Tlgd, const int* __restrict__ Tlgs,
                           const int* __restrict__ Td,
                           const int* __restrict__ rowptr, int* __restrict__ fill,
                           int* __restrict__ col){
  int e = blockIdx.x * 256 + threadIdx.x;
  if (e >= NE_ALL) return;
  int seg, srcv;
  if (e < ELG){                      seg = Glgd[e];                           srcv = Glgs[e]; }
  else if (e < ELG + EG){            int l = e - ELG;                         seg = SEG1 + Gd[l];   srcv = l; }
  else if (e < ELG + EG + ELGT){     int l = e - ELG - EG;                    seg = SEG2 + Tlgd[l]; srcv = Tlgs[l]; }
  else {                             int l = e - ELG - EG - ELGT;             seg = SEG3 + Td[l];   srcv = l; }
  int pos = atomicAdd(&fill[seg], 1);
  col[rowptr[seg] + pos] = srcv;
}

// fill the padding tail of every segment with the dummy (zero) row index
__global__ void k_fill_pad(const int* __restrict__ cnt, const int* __restrict__ rowptr,
                           int* __restrict__ col){
  int seg = blockIdx.x * 256 + threadIdx.x;
  if (seg >= NSEG_ALL) return;
  int dummy = (seg < SEG2) ? EG : ET;          // msgG dummy row / msgT dummy row
  int start = rowptr[seg] + cnt[seg];
  int end = rowptr[seg + 1];
  for (int q = start; q < end; q++) col[q] = dummy;
}

// zero the dummy msg rows (ws is poisoned 0xAA)
__global__ void k_zero_dummy(u16* a, u16* b, u16* c, u16* d){
  int i = threadIdx.x;
  if (i < 128){
    a[(size_t)EG * 128 + i] = 0; b[(size_t)EG * 128 + i] = 0;
    c[(size_t)ET * 128 + i] = 0; d[(size_t)ET * 128 + i] = 0;
  }
}

// ---------------- MFMA-gather: acc += sum_j mma(msg[col_j], Bfrag) ----------------
// Linear in msg: feeding each neighbor row directly as the A-fragment and
// accumulating in the f32 C-accumulator computes (segment_sum msg) @ W with
// zero VALU unpack/add/repack. Dummy rows (zeros) pad to wave-uniform counts.
__device__ __forceinline__ void gather_mma(const int* __restrict__ rowptr,
    const int* __restrict__ colidx, const u16* __restrict__ msg,
    int row, int M, int kg, int dummy, const u16* __restrict__ frag,
    f32x4 (&acc)[8])
{
  int lane = threadIdx.x & 63;
  const u16* fbase = frag + lane * 8;
  int p0 = 0, pe = 0;
  if (row < M){ p0 = rowptr[row]; pe = rowptr[row + 1]; }
  for (int sl = 0; __any(p0 + sl < pe); sl += 2){
    uint2 ci = *(const uint2*)(colidx + p0 + sl);
    int i0 = (p0 + sl     < pe) ? (int)ci.x : dummy;
    int i1 = (p0 + sl + 1 < pe) ? (int)ci.y : dummy;
    const uint4* b0 = (const uint4*)(msg + (size_t)i0 * 128);
    const uint4* b1 = (const uint4*)(msg + (size_t)i1 * 128);
    bf16x8 a0[4], a1[4];
    #pragma unroll
    for (int ks = 0; ks < 4; ks++){
      a0[ks] = as_frag(b0[ks * 4 + kg]);
      a1[ks] = as_frag(b1[ks * 4 + kg]);
    }
    #pragma unroll
    for (int ks = 0; ks < 4; ks++){
      const u16* fb = fbase + (size_t)ks * 4096;
      #pragma unroll
      for (int nt = 0; nt < 8; nt++){
        bf16x8 b = *(const bf16x8*)(fb + (size_t)nt * 512);   // B hoisted: 1 load / 2 MFMA
        acc[nt] = __builtin_amdgcn_mfma_f32_16x16x32_bf16(a0[ks], b, acc[nt], 0, 0, 0);
        acc[nt] = __builtin_amdgcn_mfma_f32_16x16x32_bf16(a1[ks], b, acc[nt], 0, 0, 0);
      }
    }
  }
}

// acc[nt] += A(frags in regs) @ Wfrag, KS ksteps
template<int KS>
__device__ __forceinline__ void mma_f(const bf16x8* a, const u16* __restrict__ frag,
                                      f32x4 (&acc)[8])
{
  int lane = threadIdx.x & 63;
  #pragma unroll
  for (int ks = 0; ks < KS; ks++){
    const u16* fb = frag + (size_t)ks * 4096 + lane * 8;
    #pragma unroll
    for (int nt = 0; nt < 8; nt++){
      bf16x8 b = *(const bf16x8*)(fb + (size_t)nt * 512);
      acc[nt] = __builtin_amdgcn_mfma_f32_16x16x32_bf16(a[ks], b, acc[nt], 0, 0, 0);
    }
  }
}

#define INIT_ACC(A) { _Pragma("unroll") for (int n_=0;n_<8;n_++){ A[n_][0]=0.f; A[n_][1]=0.f; A[n_][2]=0.f; A[n_][3]=0.f; } }

// tile (bf16, swizzled, wave-stripe-local) -> row-major global bf16 (nt store)
__device__ __forceinline__ void repack_store(const char* __restrict__ tile,
    u16* __restrict__ dst, int row0, int M)
{
  int rl = threadIdx.x >> 2, q = threadIdx.x & 3;
  int grow = row0 + rl;
  if (grow < M){
    #pragma unroll
    for (int v = 0; v < 4; v++){
      uint4 d = *(const uint4*)(tile + swz(rl, (v * 4 + q) * 16));
      stnt4(dst + (size_t)grow * 128 + (size_t)(v * 4 + q) * 8, d);
    }
  }
}

// frag-major uint2 slot: [blk][w][nt][lane][4 bf16]
__device__ __forceinline__ size_t fslot(int blk, int w, int nt){
  return ((((size_t)blk * 4 + w) * 8 + nt) * 64 + (threadIdx.x & 63)) * 4;
}

// load the 4 A-fragments of concat(Gf[Gsrc[arow]], Gef[arow]) for this lane
__device__ __forceinline__ void load_catfrag(const void* __restrict__ Gf,
    const void* __restrict__ Gef, const int* __restrict__ Gsrc,
    int arow, int kg, int bf, bf16x8 (&fC)[4])
{
  if (arow < EG){
    int sr = Gsrc[arow];
    const void* ra = rowdt(Gf, (size_t)sr, 64, bf);
    const void* rb = rowdt(Gef, (size_t)arow, 64, bf);
    float t[8];
    load8(ra, kg, bf, t);     fC[0] = packfrag(t);
    load8(ra, 4 + kg, bf, t); fC[1] = packfrag(t);
    load8(rb, kg, bf, t);     fC[2] = packfrag(t);
    load8(rb, 4 + kg, bf, t); fC[3] = packfrag(t);
  } else {
    #pragma unroll
    for (int ks = 0; ks < 4; ks++) fC[ks] = zfrag();
  }
}

// ---------------- merged pipeline kernels ----------------

// blocks [0,GET): xz/xr/xh = emb[Tid[Tsrc]]@{Wz,Wr,Wh}; msgT = sig(xz)*tanh(xh)
// blocks [GET,GET+GEG): msgG = relu(Gf[Gsrc]@W1 + Gef@W2)
__global__ __launch_bounds__(256, 4) void k_init(
    const void* __restrict__ Gf, const void* __restrict__ Gef, const int* __restrict__ Gsrc,
    const u16* __restrict__ fWcat, const int* __restrict__ flagp, u16* __restrict__ msgG,
    const void* __restrict__ emb, const int* __restrict__ Tid, const int* __restrict__ Tsrc,
    const u16* __restrict__ fWz, const u16* __restrict__ fWr, const u16* __restrict__ fWh,
    u16* __restrict__ xzf, u16* __restrict__ xrf, u16* __restrict__ xhf, u16* __restrict__ msgT)
{
  __shared__ char t0[TILE_B];
  int bf = *flagp;
  int lane = threadIdx.x & 63, w = threadIdx.x >> 6;
  int stripe = w * 16, kg = lane >> 4, m16 = lane & 15;
  if (blockIdx.x < GET){
    int blk = blockIdx.x, row0 = blk * 64, arow = row0 + stripe + m16;
    bf16x8 fE[4];
    if (arow < ET){
      int id = Tid[Tsrc[arow]];
      const void* rb = rowdt(emb, (size_t)id, 128, bf);
      #pragma unroll
      for (int ks = 0; ks < 4; ks++){
        float t[8]; load8(rb, ks * 4 + kg, bf, t); fE[ks] = packfrag(t);
      }
    } else {
      #pragma unroll
      for (int ks = 0; ks < 4; ks++) fE[ks] = zfrag();
    }
    f32x4 acc[8];
    uint2 zpk[8];
    INIT_ACC(acc);
    mma_f<4>(fE, fWz, acc);                       // aZ
    #pragma unroll
    for (int nt = 0; nt < 8; nt++){
      zpk[nt] = pack4(acc[nt]);
      *(uint2*)(xzf + fslot(blk, w, nt)) = zpk[nt];
    }
    INIT_ACC(acc);
    mma_f<4>(fE, fWr, acc);                       // aR
    #pragma unroll
    for (int nt = 0; nt < 8; nt++)
      *(uint2*)(xrf + fslot(blk, w, nt)) = pack4(acc[nt]);
    INIT_ACC(acc);
    mma_f<4>(fE, fWh, acc);                       // aH
    #pragma unroll
    for (int nt = 0; nt < 8; nt++){
      *(uint2*)(xhf + fslot(blk, w, nt)) = pack4(acc[nt]);
      float xzv[4]; unp4(zpk[nt], xzv);
      #pragma unroll
      for (int r = 0; r < 4; r++){
        int rt = stripe + (kg << 2) + r;
        int cb = nt * 32 + m16 * 2;
        *(u16*)(t0 + swz(rt, cb)) = f2bf(sigm(xzv[r]) * tanh_(acc[nt][r]));
      }
    }
    wfence();
    repack_store(t0, msgT, row0, ET);
  } else {
    int blk = blockIdx.x - GET, row0 = blk * 64, arow = row0 + stripe + m16;
    bf16x8 fC[4];
    load_catfrag(Gf, Gef, Gsrc, arow, kg, bf, fC);
    f32x4 acc[8]; INIT_ACC(acc);
    mma_f<4>(fC, fWcat, acc);
    #pragma unroll
    for (int nt = 0; nt < 8; nt++)
      #pragma unroll
      for (int r = 0; r < 4; r++){
        int rt = stripe + (kg << 2) + r;
        int cb = nt * 32 + m16 * 2;
        *(u16*)(t0 + swz(rt, cb)) = f2bf(relu_(acc[nt][r]));
      }
    wfence();
    repack_store(t0, msgG, row0, EG);
  }
}

// blocks [0,GET): T GRU iter (S via identity MFMA-gather, one LDS tile)
// blocks [GET,GET+GEG): G iter (segsum@W3 via MFMA-gather)
__global__ __launch_bounds__(256, 4) void k_iter(
    const u16* __restrict__ msgInG, u16* __restrict__ msgOutG,
    const void* __restrict__ Gf, const void* __restrict__ Gef, const int* __restrict__ Gsrc,
    const int* __restrict__ rp, const int* __restrict__ col,
    const u16* __restrict__ fWcat, const u16* __restrict__ fW3, const int* __restrict__ flagp,
    const u16* __restrict__ msgInT, u16* __restrict__ msgOutT,
    const u16* __restrict__ fUz, const u16* __restrict__ fUr, const u16* __restrict__ fUh,
    const u16* __restrict__ fI,
    const u16* __restrict__ xzf, const u16* __restrict__ xrf, const u16* __restrict__ xhf)
{
  __shared__ char t0[TILE_B];
  int lane = threadIdx.x & 63, w = threadIdx.x >> 6;
  int stripe = w * 16, kg = lane >> 4, m16 = lane & 15;
  if (blockIdx.x < GET){
    // ---- T GRU step ----
    int blk = blockIdx.x, row0 = blk * 64, arow = row0 + stripe + m16;
    f32x4 acc[8];
    INIT_ACC(acc);
    gather_mma(rp + SEG2, col, msgInT, arow, ET, kg, ET, fI, acc);  // S (C-layout)
    uint2 spk[8];
    #pragma unroll
    for (int nt = 0; nt < 8; nt++){
      spk[nt] = pack4(acc[nt]);
      #pragma unroll
      for (int r = 0; r < 4; r++){
        int rt = stripe + (kg << 2) + r;
        int cb = nt * 32 + m16 * 2;
        *(u16*)(t0 + swz(rt, cb)) = f2bf(acc[nt][r]);   // S tile (C-positions)
      }
    }
    wfence();
    bf16x8 fS[4];
    #pragma unroll
    for (int ks = 0; ks < 4; ks++)
      fS[ks] = *(const bf16x8*)(t0 + swz(stripe + m16, ks * 64 + kg * 16));
    INIT_ACC(acc);
    mma_f<4>(fS, fUr, acc);                      // S@Ur
    wfence();
    #pragma unroll
    for (int nt = 0; nt < 8; nt++){
      uint2 xr4 = *(const uint2*)(xrf + fslot(blk, w, nt));
      float xrv[4], sv[4];
      unp4(xr4, xrv); unp4(spk[nt], sv);
      #pragma unroll
      for (int r = 0; r < 4; r++){
        int rt = stripe + (kg << 2) + r;
        int cb = nt * 32 + m16 * 2;
        float rr = sigm(xrv[r] + acc[nt][r]);
        *(u16*)(t0 + swz(rt, cb)) = f2bf(rr * sv[r]);   // r*s tile (overwrites S; s lives in spk)
      }
    }
    wfence();
    INIT_ACC(acc);
    mma_f<4>(fS, fUz, acc);                      // S@Uz (fS still in regs)
    uint2 zpk[8];
    #pragma unroll
    for (int nt = 0; nt < 8; nt++){
      uint2 xz4 = *(const uint2*)(xzf + fslot(blk, w, nt));
      float xzv[4], zv[4];
      unp4(xz4, xzv);
      #pragma unroll
      for (int r = 0; r < 4; r++) zv[r] = sigm(xzv[r] + acc[nt][r]);
      zpk[nt] = pack4a(zv);
    }
    bf16x8 fRS[4];
    #pragma unroll
    for (int ks = 0; ks < 4; ks++)
      fRS[ks] = *(const bf16x8*)(t0 + swz(stripe + m16, ks * 64 + kg * 16));
    INIT_ACC(acc);
    mma_f<4>(fRS, fUh, acc);                     // (r*s)@Uh
    wfence();
    #pragma unroll
    for (int nt = 0; nt < 8; nt++){
      uint2 xh4 = *(const uint2*)(xhf + fslot(blk, w, nt));
      float xhv[4], sv[4], zv[4];
      unp4(xh4, xhv); unp4(spk[nt], sv); unp4(zpk[nt], zv);
      #pragma unroll
      for (int r = 0; r < 4; r++){
        int rt = stripe + (kg << 2) + r;
        int cb = nt * 32 + m16 * 2;
        float h = tanh_(xhv[r] + acc[nt][r]);
        *(u16*)(t0 + swz(rt, cb)) = f2bf((1.f - zv[r]) * sv[r] + zv[r] * h);
      }
    }
    wfence();
    repack_store(t0, msgOutT, row0, ET);
  } else {
    // ---- G iter: msgOut = relu(Gf[Gsrc]@W1 + Gef@W2 + segsum(msgIn)@W3) ----
    int bf = *flagp;
    int blk = blockIdx.x - GET, row0 = blk * 64, arow = row0 + stripe + m16;
    f32x4 acc[8]; INIT_ACC(acc);
    gather_mma(rp, col, msgInG, arow, EG, kg, EG, fW3, acc);        // segsum@W3
    bf16x8 fC[4];
    load_catfrag(Gf, Gef, Gsrc, arow, kg, bf, fC);
    mma_f<4>(fC, fWcat, acc);
    #pragma unroll
    for (int nt = 0; nt < 8; nt++)
      #pragma unroll
      for (int r = 0; r < 4; r++){
        int rt = stripe + (kg << 2) + r;
        int cb = nt * 32 + m16 * 2;
        *(u16*)(t0 + swz(rt, cb)) = f2bf(relu_(acc[nt][r]));
      }
    wfence();
    repack_store(t0, msgOutG, row0, EG);
  }
}

// blocks [0,GNT): out_T = relu(emb[Tid]@U1T + segsum(msgT)@U2T)
// blocks [GNT,GNT+GNG): out_G = relu(Gf@U1G + segsum(msgG)@U2G)
__global__ __launch_bounds__(256, 4) void k_readout(
    const void* __restrict__ Gf, const u16* __restrict__ msgG,
    const int* __restrict__ rp, const int* __restrict__ col,
    const u16* __restrict__ fU1G, const u16* __restrict__ fU2G,
    const void* __restrict__ emb, const int* __restrict__ Tid, const u16* __restrict__ msgT,
    const u16* __restrict__ fU1T, const u16* __restrict__ fU2T,
    const int* __restrict__ flagp, float* __restrict__ out)
{
  int bf = *flagp;
  int lane = threadIdx.x & 63, w = threadIdx.x >> 6;
  int stripe = w * 16, kg = lane >> 4, m16 = lane & 15;
  if (blockIdx.x < GNT){
    int row0 = blockIdx.x * 64, arow = row0 + stripe + m16;
    f32x4 acc[8]; INIT_ACC(acc);
    gather_mma(rp + SEG3, col, msgT, arow, NT, kg, ET, fU2T, acc);  // segsum@U2T
    bf16x8 fE[4];
    if (arow < NT){
      int id = Tid[arow];
      const void* rb = rowdt(emb, (size_t)id, 128, bf);
      #pragma unroll
      for (int ks = 0; ks < 4; ks++){
        float t[8]; load8(rb, ks * 4 + kg, bf, t); fE[ks] = packfrag(t);
      }
    } else {
      #pragma unroll
      for (int ks = 0; ks < 4; ks++) fE[ks] = zfrag();
    }
    mma_f<4>(fE, fU1T, acc);
    #pragma unroll
    for (int nt = 0; nt < 8; nt++)
      #pragma unroll
      for (int r = 0; r < 4; r++){
        int R = row0 + stripe + (kg << 2) + r;
        if (R < NT) __builtin_nontemporal_store(relu_(acc[nt][r]),
                        &out[(size_t)(NG + R) * 128 + nt * 16 + m16]);
      }
  } else {
    int row0 = (blockIdx.x - GNT) * 64, arow = row0 + stripe + m16;
    f32x4 acc[8]; INIT_ACC(acc);
    gather_mma(rp + SEG1, col, msgG, arow, NG, kg, EG, fU2G, acc);  // segsum@U2G
    bf16x8 fG[2];
    if (arow < NG){
      const void* ra = rowdt(Gf, (size_t)arow, 64, bf);
      float t[8];
      load8(ra, kg, bf, t);     fG[0] = packfrag(t);
      load8(ra, 4 + kg, bf, t); fG[1] = packfrag(t);
    } else { fG[0] = zfrag(); fG[1] = zfrag(); }
    mma_f<2>(fG, fU1G, acc);
    #pragma unroll
    for (int nt = 0; nt < 8; nt++)
      #pragma unroll
      for (int r = 0; r < 4; r++){
        int R = row0 + stripe + (kg << 2) + r;
        if (R < NG) __builtin_nontemporal_store(relu_(acc[nt][r]),
                        &out[(size_t)R * 128 + nt * 16 + m16]);
      }
  }
}

// ---------------- host launcher ----------------
extern "C" void kernel_launch(void* const* d_in, const int* in_sizes, int n_in,
                              void* d_out, int out_size, void* d_ws, size_t ws_size,
                              hipStream_t stream)
{
  const void* G_f      = d_in[0];
  const void* G_ef     = d_in[1];
  const int*  G_src    = (const int*)d_in[2];
  const int*  G_dst    = (const int*)d_in[3];
  const int*  G_lg_src = (const int*)d_in[4];
  const int*  G_lg_dst = (const int*)d_in[5];
  const int*  T_id     = (const int*)d_in[6];
  const int*  T_src    = (const int*)d_in[7];
  const int*  T_dst    = (const int*)d_in[8];
  const int*  T_lg_src = (const int*)d_in[9];
  const int*  T_lg_dst = (const int*)d_in[10];
  const void* emb      = d_in[11];
  float* out = (float*)d_out;
  (void)in_sizes; (void)n_in; (void)out_size; (void)ws_size;

  size_t off = 0;
  auto alloc = [&](size_t bytes) -> char* {
    char* p = (char*)d_ws + off;
    off += (bytes + 255) & ~(size_t)255;
    return p;
  };

  int*   flag = (int*)alloc(256);
  float* wm   = (float*)alloc(sizeof(float) * 188416);
  u16*   frag = (u16*)alloc(2 * 46 * 4096);
  u16*   fI   = (u16*)alloc(2 * 4 * 4096);
  const u16* fWcat = frag;
  const u16* fW3   = frag + (size_t)4  * 4096;
  const u16* fU1G  = frag + (size_t)8  * 4096;
  const u16* fU2G  = frag + (size_t)10 * 4096;
  const u16* fWz   = frag + (size_t)14 * 4096;
  const u16* fUz   = frag + (size_t)18 * 4096;
  const u16* fWr   = frag + (size_t)22 * 4096;
  const u16* fUr   = frag + (size_t)26 * 4096;
  const u16* fWh   = frag + (size_t)30 * 4096;
  const u16* fUh   = frag + (size_t)34 * 4096;
  const u16* fU1T  = frag + (size_t)38 * 4096;
  const u16* fU2T  = frag + (size_t)42 * 4096;

  int* rp   = (int*)alloc(sizeof(int) * (NSEG_ALL + 1));
  int* col  = (int*)alloc(sizeof(int) * NE_PAD);
  int* cnt  = (int*)alloc(sizeof(int) * 2 * NSEG_ALL);
  int* csum = (int*)alloc(sizeof(int) * 256);
  u16* msgGA = (u16*)alloc((size_t)(EG + 1) * 128 * 2);
  u16* msgGB = (u16*)alloc((size_t)(EG + 1) * 128 * 2);
  u16* xzf   = (u16*)alloc((size_t)GET * 8192 * 2);
  u16* xrf   = (u16*)alloc((size_t)GET * 8192 * 2);
  u16* xhf   = (u16*)alloc((size_t)GET * 8192 * 2);
  u16* msgTA = (u16*)alloc((size_t)(ET + 1) * 128 * 2);
  u16* msgTB = (u16*)alloc((size_t)(ET + 1) * 128 * 2);
  // total ws ≈ 360 MB (r8 footprint + 32 KB identity table)

  // setup: dtype flag -> weight mirrors -> fragment tables
  k_sniff<<<1, 256, 0, stream>>>((const u32*)G_ef, flag);
  k_cvt_all<<<(188416 + 255) / 256, 256, 0, stream>>>(
      d_in[12], d_in[13], d_in[14], d_in[15], d_in[16], d_in[17], d_in[18],
      d_in[19], d_in[20], d_in[21], d_in[22], d_in[23], d_in[24], wm, flag);
  k_mkfrag_all<<<46, 512, 0, stream>>>(wm, frag);
  k_mkident<<<4, 512, 0, stream>>>(fI);
  k_zero_dummy<<<1, 128, 0, stream>>>(msgGA, msgGB, msgTA, msgTB);

  // unified padded CSR build
  hipMemsetAsync(cnt, 0, sizeof(int) * 2 * NSEG_ALL, stream);
  k_hist_all<<<(NE_ALL + 255) / 256, 256, 0, stream>>>(G_lg_dst, G_dst, T_lg_dst, T_dst, cnt);
  int nch = (NSEG_ALL + 4095) / 4096;
  k_scan1<<<nch, 256, 0, stream>>>(cnt, NSEG_ALL, csum);
  k_scan2<<<1, 64, 0, stream>>>(csum, nch, rp, NSEG_ALL);
  k_scan3<<<nch, 256, 0, stream>>>(cnt, NSEG_ALL, csum, rp);
  k_fill_all<<<(NE_ALL + 255) / 256, 256, 0, stream>>>(
      G_lg_dst, G_lg_src, G_dst, T_lg_dst, T_lg_src, T_dst, rp, cnt + NSEG_ALL, col);
  k_fill_pad<<<(NSEG_ALL + 255) / 256, 256, 0, stream>>>(cnt, rp, col);

  // merged pipeline (5 launches, T blocks first)
  k_init<<<GET + GEG, 256, 0, stream>>>(G_f, G_ef, G_src, fWcat, flag, msgGA,
                                        emb, T_id, T_src, fWz, fWr, fWh, xzf, xrf, xhf, msgTA);
  k_iter<<<GET + GEG, 256, 0, stream>>>(msgGA, msgGB, G_f, G_ef, G_src, rp, col, fWcat, fW3, flag,
                                        msgTA, msgTB, fUz, fUr, fUh, fI, xzf, xrf, xhf);
  k_iter<<<GET + GEG, 256, 0, stream>>>(msgGB, msgGA, G_f, G_ef, G_src, rp, col, fWcat, fW3, flag,
                                        msgTB, msgTA, fUz, fUr, fUh, fI, xzf, xrf, xhf);
  k_iter<<<GET + GEG, 256, 0, stream>>>(msgGA, msgGB, G_f, G_ef, G_src, rp, col, fWcat, fW3, flag,
                                        msgTA, msgTB, fUz, fUr, fUh, fI, xzf, xrf, xhf);
  k_readout<<<GNT + GNG, 256, 0, stream>>>(G_f, msgGB, rp, col, fU1G, fU2G,
                                           emb, T_id, msgTB, fU1T, fU2T, flag, out);
}

// Round 11
// 1522.414 us; speedup vs baseline: 1.9993x; 1.9993x over previous
//
#include <hip/hip_runtime.h>

#define NG 100000
#define EG 400000
#define ELG 1200000
#define NT 50000
#define ET 100000
#define ELGT 300000

#define GEG ((EG + 63) / 64)     // 6250
#define GET ((ET + 63) / 64)     // 1563
#define GNG ((NG + 63) / 64)     // 1563
#define GNT ((NT + 63) / 64)     // 782

// concatenated CSR segment space: [G_lg(EG) | G_dst(NG) | T_lg(ET) | T_dst(NT)]
#define SEG1 EG
#define SEG2 (EG + NG)
#define SEG3 (EG + NG + ET)
#define NSEG_ALL (EG + NG + ET + NT)
#define NE_ALL (ELG + EG + ELGT + ET)
// padded CSR upper bound: every segment rounded up to multiple of 4
#define NE_PAD (NE_ALL + 3 * NSEG_ALL + 64)

typedef unsigned short u16;
typedef unsigned int u32;
typedef __attribute__((ext_vector_type(8))) short bf16x8;
typedef __attribute__((ext_vector_type(4))) float f32x4;
typedef __attribute__((ext_vector_type(4))) u32 u32x4;
typedef __attribute__((ext_vector_type(2))) u32 u32x2;

#define TILE_B 16384   // one 64-row x 128-col bf16 tile (row stride 256 B)

__device__ __forceinline__ float bflo(u32 p){ return __uint_as_float(p << 16); }
__device__ __forceinline__ float bfhi(u32 p){ return __uint_as_float(p & 0xffff0000u); }
__device__ __forceinline__ float bf2f(u16 h){ return __uint_as_float(((u32)h) << 16); }
__device__ __forceinline__ u16 f2bf(float f){
  u32 u = __float_as_uint(f);
  u32 r = u + 0x7fffu + ((u >> 16) & 1u);
  return (u16)(r >> 16);
}
__device__ __forceinline__ float sigm(float x){ return 1.0f / (1.0f + __expf(-x)); }
__device__ __forceinline__ float tanh_(float x){ return 2.0f / (1.0f + __expf(-2.0f * x)) - 1.0f; }
__device__ __forceinline__ float relu_(float x){ return x > 0.0f ? x : 0.0f; }
__device__ __forceinline__ void wfence(){ __builtin_amdgcn_wave_barrier(); }

// non-temporal (cache-bypass) accessors
__device__ __forceinline__ uint4 ldnt4(const void* p){
  u32x4 v = __builtin_nontemporal_load((const u32x4*)p);
  return make_uint4(v.x, v.y, v.z, v.w);
}
__device__ __forceinline__ void stnt4(void* p, uint4 d){
  u32x4 v = {d.x, d.y, d.z, d.w};
  __builtin_nontemporal_store(v, (u32x4*)p);
}
__device__ __forceinline__ uint2 ldnt2(const void* p){
  u32x2 v = __builtin_nontemporal_load((const u32x2*)p);
  return make_uint2(v.x, v.y);
}
__device__ __forceinline__ void stnt2(void* p, uint2 d){
  u32x2 v = {d.x, d.y};
  __builtin_nontemporal_store(v, (u32x2*)p);
}

// LDS tile byte swizzle (T2): row stride 256B, XOR row bits into byte bits 4-6
__device__ __forceinline__ int swz(int r, int c){ return r * 256 + (c ^ ((r & 7) << 4)); }

__device__ __forceinline__ void zero8(float v[8]){
  #pragma unroll
  for (int j = 0; j < 8; j++) v[j] = 0.f;
}
__device__ __forceinline__ uint4 pack8(const float v[8]){
  uint4 o;
  o.x = f2bf(v[0]) | ((u32)f2bf(v[1]) << 16);
  o.y = f2bf(v[2]) | ((u32)f2bf(v[3]) << 16);
  o.z = f2bf(v[4]) | ((u32)f2bf(v[5]) << 16);
  o.w = f2bf(v[6]) | ((u32)f2bf(v[7]) << 16);
  return o;
}
__device__ __forceinline__ uint2 pack4(const f32x4& a){
  uint2 o;
  o.x = (u32)f2bf(a[0]) | ((u32)f2bf(a[1]) << 16);
  o.y = (u32)f2bf(a[2]) | ((u32)f2bf(a[3]) << 16);
  return o;
}
__device__ __forceinline__ void unp4(uint2 u, float v[4]){
  v[0] = bflo(u.x); v[1] = bfhi(u.x); v[2] = bflo(u.y); v[3] = bfhi(u.y);
}
__device__ __forceinline__ bf16x8 packfrag(const float v[8]){
  union { uint4 u; bf16x8 b; } c; c.u = pack8(v); return c.b;
}
__device__ __forceinline__ bf16x8 zfrag(){
  union { uint4 u; bf16x8 b; } c; c.u = make_uint4(0, 0, 0, 0); return c.b;
}
__device__ __forceinline__ bf16x8 as_frag(uint4 u){
  union { uint4 u; bf16x8 b; } c; c.u = u; return c.b;
}

// ---------------- dtype sniffer (bf16 vs f32 inputs) ----------------
__global__ void k_sniff(const u32* __restrict__ g, int* __restrict__ flag){
  __shared__ int sh[2];
  if (threadIdx.x < 2) sh[threadIdx.x] = 0;
  __syncthreads();
  int c0 = 0, c1 = 0;
  for (int i = 0; i < 16; i++){
    u32 w = g[threadIdx.x * 16 + i];
    u32 lo = w & 0xFFFFu;
    if (lo == 0u) c0++;
    else { u32 e = (lo >> 7) & 0xFFu; if (e >= 96u && e <= 144u) c1++; }
  }
  atomicAdd(&sh[0], c0); atomicAdd(&sh[1], c1);
  __syncthreads();
  if (threadIdx.x == 0) *flag = (sh[0] < 512 && sh[1] > 2048) ? 1 : 0;
}

// all 13 weights -> f32 mirror arena (one launch)
__global__ void k_cvt_all(const void* p0, const void* p1, const void* p2, const void* p3,
                          const void* p4, const void* p5, const void* p6, const void* p7,
                          const void* p8, const void* p9, const void* p10, const void* p11,
                          const void* p12, float* __restrict__ wm, const int* __restrict__ flagp){
  int i = blockIdx.x * 256 + threadIdx.x;
  if (i >= 188416) return;
  const int offs[14] = {0,8192,16384,32768,40960,57344,73728,90112,106496,122880,139264,155648,172032,188416};
  const void* ps[13] = {p0,p1,p2,p3,p4,p5,p6,p7,p8,p9,p10,p11,p12};
  int w = 0;
  while (i >= offs[w + 1]) w++;
  int li = i - offs[w];
  wm[i] = (*flagp) ? bf2f(((const u16*)ps[w])[li]) : ((const float*)ps[w])[li];
}

// all MFMA B-fragment tables (one launch, 46 ks-blocks)
__global__ void k_mkfrag_all(const float* __restrict__ wm, u16* __restrict__ frag){
  const int wmo[13] = {0,8192,16384,32768,40960,57344,73728,90112,106496,122880,139264,155648,172032};
  const int nks[13] = {2,2,4,2,4,4,4,4,4,4,4,4,4};
  int b = blockIdx.x;            // 0..45
  int wi = 0, ks = b;
  while (ks >= nks[wi]){ ks -= nks[wi]; wi++; }
  const float* W = wm + wmo[wi];
  int nt = threadIdx.x >> 6, lane = threadIdx.x & 63;
  int kr = ks * 32 + ((lane >> 4) << 3);
  int col = nt * 16 + (lane & 15);
  u16* o = frag + (size_t)b * 4096 + nt * 512 + lane * 8;
  #pragma unroll
  for (int j = 0; j < 8; j++) o[j] = f2bf(W[(size_t)(kr + j) * 128 + col]);
}

// ---------------- dual-dtype row access ----------------
__device__ __forceinline__ const void* rowdt(const void* mat, size_t row, int W, int bf){
  return bf ? (const void*)((const u16*)mat + row * (size_t)W)
            : (const void*)((const float*)mat + row * (size_t)W);
}
__device__ __forceinline__ void load8(const void* rowbase, int c8, int bf, float v[8]){
  if (bf){
    uint4 d = ((const uint4*)rowbase)[c8];
    v[0]=bflo(d.x); v[1]=bfhi(d.x); v[2]=bflo(d.y); v[3]=bfhi(d.y);
    v[4]=bflo(d.z); v[5]=bfhi(d.z); v[6]=bflo(d.w); v[7]=bfhi(d.w);
  } else {
    const float4* p = (const float4*)rowbase + (c8 << 1);
    float4 a = p[0], b = p[1];
    v[0]=a.x; v[1]=a.y; v[2]=a.z; v[3]=a.w; v[4]=b.x; v[5]=b.y; v[6]=b.z; v[7]=b.w;
  }
}
// non-temporal variant (read-once streams)
__device__ __forceinline__ void load8_nt(const void* rowbase, int c8, int bf, float v[8]){
  if (bf){
    uint4 d = ldnt4((const uint4*)rowbase + c8);
    v[0]=bflo(d.x); v[1]=bfhi(d.x); v[2]=bflo(d.y); v[3]=bfhi(d.y);
    v[4]=bflo(d.z); v[5]=bfhi(d.z); v[6]=bflo(d.w); v[7]=bfhi(d.w);
  } else {
    uint4 a = ldnt4((const float4*)rowbase + (c8 << 1));
    uint4 b = ldnt4((const float4*)rowbase + (c8 << 1) + 1);
    v[0]=__uint_as_float(a.x); v[1]=__uint_as_float(a.y);
    v[2]=__uint_as_float(a.z); v[3]=__uint_as_float(a.w);
    v[4]=__uint_as_float(b.x); v[5]=__uint_as_float(b.y);
    v[6]=__uint_as_float(b.z); v[7]=__uint_as_float(b.w);
  }
}

// ---------------- unified CSR build (padded to multiples of 4) ----------------
__global__ void k_hist_all(const int* __restrict__ Glgd, const int* __restrict__ Gd,
                           const int* __restrict__ Tlgd, const int* __restrict__ Td,
                           int* __restrict__ cnt){
  int e = blockIdx.x * 256 + threadIdx.x;
  if (e >= NE_ALL) return;
  int seg;
  if (e < ELG)                       seg = Glgd[e];
  else if (e < ELG + EG)             seg = SEG1 + Gd[e - ELG];
  else if (e < ELG + EG + ELGT)      seg = SEG2 + Tlgd[e - ELG - EG];
  else                               seg = SEG3 + Td[e - ELG - EG - ELGT];
  atomicAdd(&cnt[seg], 1);
}

__global__ void k_scan1(const int* __restrict__ cnt, int n, int* __restrict__ csum){
  int base = blockIdx.x * 4096, tid = threadIdx.x;
  int s = 0;
  for (int i = 0; i < 16; i++){
    int idx = base + i * 256 + tid;
    if (idx < n) s += (cnt[idx] + 3) & ~3;      // padded count
  }
  __shared__ int red[4];
  for (int off = 32; off; off >>= 1) s += __shfl_down(s, off, 64);
  if ((tid & 63) == 0) red[tid >> 6] = s;
  __syncthreads();
  if (tid == 0) csum[blockIdx.x] = red[0] + red[1] + red[2] + red[3];
}

__global__ void k_scan2(int* csum, int nch, int* rowptr, int n){
  if (threadIdx.x == 0){
    int run = 0;
    for (int c = 0; c < nch; c++){ int t = csum[c]; csum[c] = run; run += t; }
    rowptr[n] = run;
  }
}

__global__ void k_scan3(const int* __restrict__ cnt, int n, const int* __restrict__ csum,
                        int* __restrict__ rowptr){
  __shared__ int buf[4096];
  __shared__ int tsum[256];
  int base = blockIdx.x * 4096, tid = threadIdx.x;
  for (int i = 0; i < 16; i++){
    int idx = base + i * 256 + tid;
    buf[i * 256 + tid] = (idx < n) ? ((cnt[idx] + 3) & ~3) : 0;   // padded count
  }
  __syncthreads();
  int run = 0;
  for (int i = 0; i < 16; i++){ int v = buf[tid * 16 + i]; buf[tid * 16 + i] = run; run += v; }
  tsum[tid] = run;
  __syncthreads();
  for (int off = 1; off < 256; off <<= 1){
    int v = (tid >= off) ? tsum[tid - off] : 0;
    __syncthreads();
    tsum[tid] += v;
    __syncthreads();
  }
  int texcl = tsum[tid] - run;
  int cbase = csum[blockIdx.x];
  for (int i = 0; i < 16; i++){
    int idx = base + tid * 16 + i;
    if (idx < n) rowptr[idx] = cbase + texcl + buf[tid * 16 + i];
  }
}

__global__ void k_fill_all(const int* __restrict__ Glgd, const int* __restrict__ Glgs,
                           const int* __restrict__ Gd,
                           const int* __restrict__ Tlgd, const int* __restrict__ Tlgs,
                           const int* __restrict__ Td,
                           const int* __restrict__ rowptr, int* __restrict__ fill,
                           int* __restrict__ col){
  int e = blockIdx.x * 256 + threadIdx.x;
  if (e >= NE_ALL) return;
  int seg, srcv;
  if (e < ELG){                      seg = Glgd[e];                           srcv = Glgs[e]; }
  else if (e < ELG + EG){            int l = e - ELG;                         seg = SEG1 + Gd[l];   srcv = l; }
  else if (e < ELG + EG + ELGT){     int l = e - ELG - EG;                    seg = SEG2 + Tlgd[l]; srcv = Tlgs[l]; }
  else {                             int l = e - ELG - EG - ELGT;             seg = SEG3 + Td[l];   srcv = l; }
  int pos = atomicAdd(&fill[seg], 1);
  col[rowptr[seg] + pos] = srcv;
}

// fill the padding tail of every segment with the dummy (zero) row index
__global__ void k_fill_pad(const int* __restrict__ cnt, const int* __restrict__ rowptr,
                           int* __restrict__ col){
  int seg = blockIdx.x * 256 + threadIdx.x;
  if (seg >= NSEG_ALL) return;
  int dummy = (seg < SEG2) ? EG : ET;          // msgG dummy row / msgT dummy row
  int start = rowptr[seg] + cnt[seg];
  int end = rowptr[seg + 1];
  for (int q = start; q < end; q++) col[q] = dummy;
}

// zero the dummy msg rows (ws is poisoned 0xAA)
__global__ void k_zero_dummy(u16* a, u16* b, u16* c, u16* d){
  int i = threadIdx.x;
  if (i < 128){
    a[(size_t)EG * 128 + i] = 0; b[(size_t)EG * 128 + i] = 0;
    c[(size_t)ET * 128 + i] = 0; d[(size_t)ET * 128 + i] = 0;
  }
}

// ---------------- register-direct gather + MFMA ----------------

__device__ __forceinline__ void acc8_add(float (&a)[8], uint4 d){
  a[0] += bflo(d.x); a[1] += bfhi(d.x);
  a[2] += bflo(d.y); a[3] += bfhi(d.y);
  a[4] += bflo(d.z); a[5] += bfhi(d.z);
  a[6] += bflo(d.w); a[7] += bfhi(d.w);
}

// CSR gather-sum (rows padded to x4, rowptr 4-aligned) of bf16 msg rows into
// A-fragment accumulators. colidx batch loaded as one uint4.
__device__ __forceinline__ void gather_accum(const int* __restrict__ rowptr,
    const int* __restrict__ colidx, const u16* __restrict__ msg,
    int row, int M, int kg, float (&acc)[4][8])
{
  #pragma unroll
  for (int ks = 0; ks < 4; ks++) zero8(acc[ks]);
  if (row >= M) return;
  int p = rowptr[row], pe = rowptr[row + 1];
  for (; p < pe; p += 4){
    uint4 ci = *(const uint4*)(colidx + p);
    const uint4* b0 = (const uint4*)(msg + (size_t)ci.x * 128);
    const uint4* b1 = (const uint4*)(msg + (size_t)ci.y * 128);
    const uint4* b2 = (const uint4*)(msg + (size_t)ci.z * 128);
    const uint4* b3 = (const uint4*)(msg + (size_t)ci.w * 128);
    uint4 v0[4], v1[4], v2[4], v3[4];
    #pragma unroll
    for (int ks = 0; ks < 4; ks++){
      v0[ks] = b0[ks * 4 + kg]; v1[ks] = b1[ks * 4 + kg];
      v2[ks] = b2[ks * 4 + kg]; v3[ks] = b3[ks * 4 + kg];
    }
    #pragma unroll
    for (int ks = 0; ks < 4; ks++){
      acc8_add(acc[ks], v0[ks]); acc8_add(acc[ks], v1[ks]);
      acc8_add(acc[ks], v2[ks]); acc8_add(acc[ks], v3[ks]);
    }
  }
}

// acc[nt] += A(frags in regs) @ Wfrag, KS ksteps
template<int KS>
__device__ __forceinline__ void mma_f(const bf16x8* a, const u16* __restrict__ frag,
                                      f32x4 (&acc)[8])
{
  int lane = threadIdx.x & 63;
  #pragma unroll
  for (int ks = 0; ks < KS; ks++){
    const u16* fb = frag + (size_t)ks * 4096 + lane * 8;
    #pragma unroll
    for (int nt = 0; nt < 8; nt++){
      bf16x8 b = *(const bf16x8*)(fb + (size_t)nt * 512);
      acc[nt] = __builtin_amdgcn_mfma_f32_16x16x32_bf16(a[ks], b, acc[nt], 0, 0, 0);
    }
  }
}

#define INIT_ACC(A) { _Pragma("unroll") for (int n_=0;n_<8;n_++){ A[n_][0]=0.f; A[n_][1]=0.f; A[n_][2]=0.f; A[n_][3]=0.f; } }

// tile (bf16, swizzled, wave-stripe-local) -> row-major global bf16 (nt store)
__device__ __forceinline__ void repack_store(const char* __restrict__ tile,
    u16* __restrict__ dst, int row0, int M)
{
  int rl = threadIdx.x >> 2, q = threadIdx.x & 3;
  int grow = row0 + rl;
  if (grow < M){
    #pragma unroll
    for (int v = 0; v < 4; v++){
      uint4 d = *(const uint4*)(tile + swz(rl, (v * 4 + q) * 16));
      stnt4(dst + (size_t)grow * 128 + (size_t)(v * 4 + q) * 8, d);
    }
  }
}

// frag-major uint2 slot: [blk][w][nt][lane][4 bf16]
__device__ __forceinline__ size_t fslot(int blk, int w, int nt){
  return ((((size_t)blk * 4 + w) * 8 + nt) * 64 + (threadIdx.x & 63)) * 4;
}

// load the 4 A-fragments of concat(Gf[Gsrc[arow]], Gef[arow]) for this lane
// Gf: cached (13 MB, random-reused); Gef: non-temporal (read-once stream)
__device__ __forceinline__ void load_catfrag(const void* __restrict__ Gf,
    const void* __restrict__ Gef, const int* __restrict__ Gsrc,
    int arow, int kg, int bf, bf16x8 (&fC)[4])
{
  if (arow < EG){
    int sr = Gsrc[arow];
    const void* ra = rowdt(Gf, (size_t)sr, 64, bf);
    const void* rb = rowdt(Gef, (size_t)arow, 64, bf);
    float t[8];
    load8(ra, kg, bf, t);        fC[0] = packfrag(t);
    load8(ra, 4 + kg, bf, t);    fC[1] = packfrag(t);
    load8_nt(rb, kg, bf, t);     fC[2] = packfrag(t);
    load8_nt(rb, 4 + kg, bf, t); fC[3] = packfrag(t);
  } else {
    #pragma unroll
    for (int ks = 0; ks < 4; ks++) fC[ks] = zfrag();
  }
}

// ---------------- pipeline kernels ----------------

// blocks [0,GET): xz/xr/xh = emb[Tid[Tsrc]]@{Wz,Wr,Wh}; msgT = sig(xz)*tanh(xh)
// blocks [GET,GET+GEG): msgG = relu(Gf[Gsrc]@W1 + Gef@W2)
__global__ __launch_bounds__(256, 5) void k_init(
    const void* __restrict__ Gf, const void* __restrict__ Gef, const int* __restrict__ Gsrc,
    const u16* __restrict__ fWcat, const int* __restrict__ flagp, u16* __restrict__ msgG,
    const void* __restrict__ emb, const int* __restrict__ Tid, const int* __restrict__ Tsrc,
    const u16* __restrict__ fWz, const u16* __restrict__ fWr, const u16* __restrict__ fWh,
    u16* __restrict__ xzf, u16* __restrict__ xrf, u16* __restrict__ xhf, u16* __restrict__ msgT)
{
  __shared__ char t0[TILE_B];
  int bf = *flagp;
  int lane = threadIdx.x & 63, w = threadIdx.x >> 6;
  int stripe = w * 16, kg = lane >> 4, m16 = lane & 15;
  if (blockIdx.x < GET){
    int blk = blockIdx.x, row0 = blk * 64, arow = row0 + stripe + m16;
    bf16x8 fE[4];
    if (arow < ET){
      int id = Tid[Tsrc[arow]];
      const void* rb = rowdt(emb, (size_t)id, 128, bf);
      #pragma unroll
      for (int ks = 0; ks < 4; ks++){
        float t[8]; load8(rb, ks * 4 + kg, bf, t); fE[ks] = packfrag(t);
      }
    } else {
      #pragma unroll
      for (int ks = 0; ks < 4; ks++) fE[ks] = zfrag();
    }
    f32x4 acc[8];
    uint2 zpk[8];
    INIT_ACC(acc);
    mma_f<4>(fE, fWz, acc);                       // aZ
    #pragma unroll
    for (int nt = 0; nt < 8; nt++){
      zpk[nt] = pack4(acc[nt]);
      stnt2(xzf + fslot(blk, w, nt), zpk[nt]);
    }
    INIT_ACC(acc);
    mma_f<4>(fE, fWr, acc);                       // aR
    #pragma unroll
    for (int nt = 0; nt < 8; nt++)
      stnt2(xrf + fslot(blk, w, nt), pack4(acc[nt]));
    INIT_ACC(acc);
    mma_f<4>(fE, fWh, acc);                       // aH
    #pragma unroll
    for (int nt = 0; nt < 8; nt++){
      stnt2(xhf + fslot(blk, w, nt), pack4(acc[nt]));
      float xzv[4]; unp4(zpk[nt], xzv);
      #pragma unroll
      for (int r = 0; r < 4; r++){
        int rt = stripe + (kg << 2) + r;
        int cb = nt * 32 + m16 * 2;
        *(u16*)(t0 + swz(rt, cb)) = f2bf(sigm(xzv[r]) * tanh_(acc[nt][r]));
      }
    }
    wfence();
    repack_store(t0, msgT, row0, ET);
  } else {
    int blk = blockIdx.x - GET, row0 = blk * 64, arow = row0 + stripe + m16;
    bf16x8 fC[4];
    load_catfrag(Gf, Gef, Gsrc, arow, kg, bf, fC);
    f32x4 acc[8]; INIT_ACC(acc);
    mma_f<4>(fC, fWcat, acc);
    #pragma unroll
    for (int nt = 0; nt < 8; nt++)
      #pragma unroll
      for (int r = 0; r < 4; r++){
        int rt = stripe + (kg << 2) + r;
        int cb = nt * 32 + m16 * 2;
        *(u16*)(t0 + swz(rt, cb)) = f2bf(relu_(acc[nt][r]));
      }
    wfence();
    repack_store(t0, msgG, row0, EG);
  }
}

// G iter: msgOut = relu(Gf[Gsrc]@W1 + Gef@W2 + segsum(msgIn)@W3)
// 16 KB LDS -> high occupancy for the latency-bound gather
__global__ __launch_bounds__(256, 5) void k_iterG(
    const u16* __restrict__ msgIn, u16* __restrict__ msgOut,
    const void* __restrict__ Gf, const void* __restrict__ Gef, const int* __restrict__ Gsrc,
    const int* __restrict__ rp, const int* __restrict__ col,
    const u16* __restrict__ fWcat, const u16* __restrict__ fW3, const int* __restrict__ flagp)
{
  __shared__ char t0[TILE_B];
  int lane = threadIdx.x & 63, w = threadIdx.x >> 6;
  int stripe = w * 16, kg = lane >> 4, m16 = lane & 15;
  int bf = *flagp;
  int row0 = blockIdx.x * 64, arow = row0 + stripe + m16;
  float ga[4][8];
  gather_accum(rp, col, msgIn, arow, EG, kg, ga);
  bf16x8 fS[4];
  #pragma unroll
  for (int ks = 0; ks < 4; ks++) fS[ks] = packfrag(ga[ks]);
  bf16x8 fC[4];
  load_catfrag(Gf, Gef, Gsrc, arow, kg, bf, fC);   // latency hides under fS@W3 mma
  f32x4 acc[8]; INIT_ACC(acc);
  mma_f<4>(fS, fW3, acc);
  mma_f<4>(fC, fWcat, acc);
  #pragma unroll
  for (int nt = 0; nt < 8; nt++)
    #pragma unroll
    for (int r = 0; r < 4; r++){
      int rt = stripe + (kg << 2) + r;
      int cb = nt * 32 + m16 * 2;
      *(u16*)(t0 + swz(rt, cb)) = f2bf(relu_(acc[nt][r]));
    }
  wfence();
  repack_store(t0, msgOut, row0, EG);
}

// T GRU iter (sequential accumulator, S + scratch LDS tiles, 32 KB LDS)
__global__ __launch_bounds__(256, 4) void k_iterT(
    const u16* __restrict__ msgIn, u16* __restrict__ msgOut,
    const int* __restrict__ rp, const int* __restrict__ col,
    const u16* __restrict__ fUz, const u16* __restrict__ fUr, const u16* __restrict__ fUh,
    const u16* __restrict__ xzf, const u16* __restrict__ xrf, const u16* __restrict__ xhf)
{
  __shared__ char t0[TILE_B];
  __shared__ char t1[TILE_B];
  int lane = threadIdx.x & 63, w = threadIdx.x >> 6;
  int stripe = w * 16, kg = lane >> 4, m16 = lane & 15;
  int blk = blockIdx.x, row0 = blk * 64, arow = row0 + stripe + m16;
  float ga[4][8];
  gather_accum(rp + SEG2, col, msgIn, arow, ET, kg, ga);
  bf16x8 fS[4];
  #pragma unroll
  for (int ks = 0; ks < 4; ks++){
    uint4 pk = pack8(ga[ks]);
    *(uint4*)(t0 + swz(stripe + m16, ks * 64 + kg * 16)) = pk;  // S tile
    fS[ks] = as_frag(pk);
  }
  f32x4 acc[8];
  INIT_ACC(acc);
  mma_f<4>(fS, fUr, acc);                      // aR
  wfence();
  #pragma unroll
  for (int nt = 0; nt < 8; nt++){
    uint2 r4 = ldnt2(xrf + fslot(blk, w, nt));
    float xrv[4]; unp4(r4, xrv);
    #pragma unroll
    for (int r = 0; r < 4; r++){
      int rt = stripe + (kg << 2) + r;
      int cb = nt * 32 + m16 * 2;
      float s = bf2f(*(const u16*)(t0 + swz(rt, cb)));
      float rr = sigm(xrv[r] + acc[nt][r]);
      *(u16*)(t1 + swz(rt, cb)) = f2bf(rr * s);   // r*s tile
    }
  }
  wfence();
  bf16x8 fRS[4];
  #pragma unroll
  for (int ks = 0; ks < 4; ks++)
    fRS[ks] = *(const bf16x8*)(t1 + swz(stripe + m16, ks * 64 + kg * 16));
  INIT_ACC(acc);
  mma_f<4>(fRS, fUh, acc);                     // aH
  wfence();
  #pragma unroll
  for (int nt = 0; nt < 8; nt++){
    uint2 h4 = ldnt2(xhf + fslot(blk, w, nt));
    float xhv[4]; unp4(h4, xhv);
    #pragma unroll
    for (int r = 0; r < 4; r++){
      int rt = stripe + (kg << 2) + r;
      int cb = nt * 32 + m16 * 2;
      *(u16*)(t1 + swz(rt, cb)) = f2bf(tanh_(xhv[r] + acc[nt][r]));   // h tile
    }
  }
  wfence();
  bf16x8 fS2[4];
  #pragma unroll
  for (int ks = 0; ks < 4; ks++)
    fS2[ks] = *(const bf16x8*)(t0 + swz(stripe + m16, ks * 64 + kg * 16));
  INIT_ACC(acc);
  mma_f<4>(fS2, fUz, acc);                     // aZ
  wfence();
  #pragma unroll
  for (int nt = 0; nt < 8; nt++){
    uint2 z4 = ldnt2(xzf + fslot(blk, w, nt));
    float xzv[4]; unp4(z4, xzv);
    #pragma unroll
    for (int r = 0; r < 4; r++){
      int rt = stripe + (kg << 2) + r;
      int cb = nt * 32 + m16 * 2;
      float z = sigm(xzv[r] + acc[nt][r]);
      float s = bf2f(*(const u16*)(t0 + swz(rt, cb)));
      float h = bf2f(*(const u16*)(t1 + swz(rt, cb)));
      *(u16*)(t0 + swz(rt, cb)) = f2bf((1.f - z) * s + z * h);
    }
  }
  wfence();
  repack_store(t0, msgOut, row0, ET);
}

// blocks [0,GNT): out_T = relu(emb[Tid]@U1T + segsum(msgT)@U2T)
// blocks [GNT,GNT+GNG): out_G = relu(Gf@U1G + segsum(msgG)@U2G)   (LDS-free)
__global__ __launch_bounds__(256, 5) void k_readout(
    const void* __restrict__ Gf, const u16* __restrict__ msgG,
    const int* __restrict__ rp, const int* __restrict__ col,
    const u16* __restrict__ fU1G, const u16* __restrict__ fU2G,
    const void* __restrict__ emb, const int* __restrict__ Tid, const u16* __restrict__ msgT,
    const u16* __restrict__ fU1T, const u16* __restrict__ fU2T,
    const int* __restrict__ flagp, float* __restrict__ out)
{
  int bf = *flagp;
  int lane = threadIdx.x & 63, w = threadIdx.x >> 6;
  int stripe = w * 16, kg = lane >> 4, m16 = lane & 15;
  if (blockIdx.x < GNT){
    int row0 = blockIdx.x * 64, arow = row0 + stripe + m16;
    float ga[4][8];
    gather_accum(rp + SEG3, col, msgT, arow, NT, kg, ga);
    bf16x8 fS[4];
    #pragma unroll
    for (int ks = 0; ks < 4; ks++) fS[ks] = packfrag(ga[ks]);
    bf16x8 fE[4];
    if (arow < NT){
      int id = Tid[arow];
      const void* rb = rowdt(emb, (size_t)id, 128, bf);
      #pragma unroll
      for (int ks = 0; ks < 4; ks++){
        float t[8]; load8(rb, ks * 4 + kg, bf, t); fE[ks] = packfrag(t);
      }
    } else {
      #pragma unroll
      for (int ks = 0; ks < 4; ks++) fE[ks] = zfrag();
    }
    f32x4 acc[8]; INIT_ACC(acc);
    mma_f<4>(fS, fU2T, acc);
    mma_f<4>(fE, fU1T, acc);
    #pragma unroll
    for (int nt = 0; nt < 8; nt++)
      #pragma unroll
      for (int r = 0; r < 4; r++){
        int R = row0 + stripe + (kg << 2) + r;
        if (R < NT) __builtin_nontemporal_store(relu_(acc[nt][r]),
                        &out[(size_t)(NG + R) * 128 + nt * 16 + m16]);
      }
  } else {
    int row0 = (blockIdx.x - GNT) * 64, arow = row0 + stripe + m16;
    float ga[4][8];
    gather_accum(rp + SEG1, col, msgG, arow, NG, kg, ga);
    bf16x8 fS[4];
    #pragma unroll
    for (int ks = 0; ks < 4; ks++) fS[ks] = packfrag(ga[ks]);
    bf16x8 fG[2];
    if (arow < NG){
      const void* ra = rowdt(Gf, (size_t)arow, 64, bf);
      float t[8];
      load8_nt(ra, kg, bf, t);     fG[0] = packfrag(t);
      load8_nt(ra, 4 + kg, bf, t); fG[1] = packfrag(t);
    } else { fG[0] = zfrag(); fG[1] = zfrag(); }
    f32x4 acc[8]; INIT_ACC(acc);
    mma_f<4>(fS, fU2G, acc);
    mma_f<2>(fG, fU1G, acc);
    #pragma unroll
    for (int nt = 0; nt < 8; nt++)
      #pragma unroll
      for (int r = 0; r < 4; r++){
        int R = row0 + stripe + (kg << 2) + r;
        if (R < NG) __builtin_nontemporal_store(relu_(acc[nt][r]),
                        &out[(size_t)R * 128 + nt * 16 + m16]);
      }
  }
}

// ---------------- host launcher ----------------
extern "C" void kernel_launch(void* const* d_in, const int* in_sizes, int n_in,
                              void* d_out, int out_size, void* d_ws, size_t ws_size,
                              hipStream_t stream)
{
  const void* G_f      = d_in[0];
  const void* G_ef     = d_in[1];
  const int*  G_src    = (const int*)d_in[2];
  const int*  G_dst    = (const int*)d_in[3];
  const int*  G_lg_src = (const int*)d_in[4];
  const int*  G_lg_dst = (const int*)d_in[5];
  const int*  T_id     = (const int*)d_in[6];
  const int*  T_src    = (const int*)d_in[7];
  const int*  T_dst    = (const int*)d_in[8];
  const int*  T_lg_src = (const int*)d_in[9];
  const int*  T_lg_dst = (const int*)d_in[10];
  const void* emb      = d_in[11];
  float* out = (float*)d_out;
  (void)in_sizes; (void)n_in; (void)out_size; (void)ws_size;

  size_t off = 0;
  auto alloc = [&](size_t bytes) -> char* {
    char* p = (char*)d_ws + off;
    off += (bytes + 255) & ~(size_t)255;
    return p;
  };

  int*   flag = (int*)alloc(256);
  float* wm   = (float*)alloc(sizeof(float) * 188416);
  u16*   frag = (u16*)alloc(2 * 46 * 4096);
  const u16* fWcat = frag;
  const u16* fW3   = frag + (size_t)4  * 4096;
  const u16* fU1G  = frag + (size_t)8  * 4096;
  const u16* fU2G  = frag + (size_t)10 * 4096;
  const u16* fWz   = frag + (size_t)14 * 4096;
  const u16* fUz   = frag + (size_t)18 * 4096;
  const u16* fWr   = frag + (size_t)22 * 4096;
  const u16* fUr   = frag + (size_t)26 * 4096;
  const u16* fWh   = frag + (size_t)30 * 4096;
  const u16* fUh   = frag + (size_t)34 * 4096;
  const u16* fU1T  = frag + (size_t)38 * 4096;
  const u16* fU2T  = frag + (size_t)42 * 4096;

  int* rp   = (int*)alloc(sizeof(int) * (NSEG_ALL + 1));
  int* col  = (int*)alloc(sizeof(int) * NE_PAD);
  int* cnt  = (int*)alloc(sizeof(int) * 2 * NSEG_ALL);
  int* csum = (int*)alloc(sizeof(int) * 256);
  u16* msgGA = (u16*)alloc((size_t)(EG + 1) * 128 * 2);
  u16* msgGB = (u16*)alloc((size_t)(EG + 1) * 128 * 2);
  u16* xzf   = (u16*)alloc((size_t)GET * 8192 * 2);
  u16* xrf   = (u16*)alloc((size_t)GET * 8192 * 2);
  u16* xhf   = (u16*)alloc((size_t)GET * 8192 * 2);
  u16* msgTA = (u16*)alloc((size_t)(ET + 1) * 128 * 2);
  u16* msgTB = (u16*)alloc((size_t)(ET + 1) * 128 * 2);
  // total ws ≈ 360 MB (r8 footprint)

  // setup: dtype flag -> weight mirrors -> fragment tables
  k_sniff<<<1, 256, 0, stream>>>((const u32*)G_ef, flag);
  k_cvt_all<<<(188416 + 255) / 256, 256, 0, stream>>>(
      d_in[12], d_in[13], d_in[14], d_in[15], d_in[16], d_in[17], d_in[18],
      d_in[19], d_in[20], d_in[21], d_in[22], d_in[23], d_in[24], wm, flag);
  k_mkfrag_all<<<46, 512, 0, stream>>>(wm, frag);
  k_zero_dummy<<<1, 128, 0, stream>>>(msgGA, msgGB, msgTA, msgTB);

  // unified padded CSR build
  hipMemsetAsync(cnt, 0, sizeof(int) * 2 * NSEG_ALL, stream);
  k_hist_all<<<(NE_ALL + 255) / 256, 256, 0, stream>>>(G_lg_dst, G_dst, T_lg_dst, T_dst, cnt);
  int nch = (NSEG_ALL + 4095) / 4096;
  k_scan1<<<nch, 256, 0, stream>>>(cnt, NSEG_ALL, csum);
  k_scan2<<<1, 64, 0, stream>>>(csum, nch, rp, NSEG_ALL);
  k_scan3<<<nch, 256, 0, stream>>>(cnt, NSEG_ALL, csum, rp);
  k_fill_all<<<(NE_ALL + 255) / 256, 256, 0, stream>>>(
      G_lg_dst, G_lg_src, G_dst, T_lg_dst, T_lg_src, T_dst, rp, cnt + NSEG_ALL, col);
  k_fill_pad<<<(NSEG_ALL + 255) / 256, 256, 0, stream>>>(cnt, rp, col);

  // pipeline: init, 3x (G iter + T iter), readout
  k_init<<<GET + GEG, 256, 0, stream>>>(G_f, G_ef, G_src, fWcat, flag, msgGA,
                                        emb, T_id, T_src, fWz, fWr, fWh, xzf, xrf, xhf, msgTA);
  k_iterG<<<GEG, 256, 0, stream>>>(msgGA, msgGB, G_f, G_ef, G_src, rp, col, fWcat, fW3, flag);
  k_iterT<<<GET, 256, 0, stream>>>(msgTA, msgTB, rp, col, fUz, fUr, fUh, xzf, xrf, xhf);
  k_iterG<<<GEG, 256, 0, stream>>>(msgGB, msgGA, G_f, G_ef, G_src, rp, col, fWcat, fW3, flag);
  k_iterT<<<GET, 256, 0, stream>>>(msgTB, msgTA, rp, col, fUz, fUr, fUh, xzf, xrf, xhf);
  k_iterG<<<GEG, 256, 0, stream>>>(msgGA, msgGB, G_f, G_ef, G_src, rp, col, fWcat, fW3, flag);
  k_iterT<<<GET, 256, 0, stream>>>(msgTA, msgTB, rp, col, fUz, fUr, fUh, xzf, xrf, xhf);
  k_readout<<<GNT + GNG, 256, 0, stream>>>(G_f, msgGB, rp, col, fU1G, fU2G,
                                           emb, T_id, msgTB, fU1T, fU2T, flag, out);
}

// Round 12
// 1248.590 us; speedup vs baseline: 2.4378x; 1.2193x over previous
//
#include <hip/hip_runtime.h>

#define NG 100000
#define EG 400000
#define ELG 1200000
#define NT 50000
#define ET 100000
#define ELGT 300000

#define GEG ((EG + 63) / 64)     // 6250
#define GET ((ET + 63) / 64)     // 1563
#define GNG ((NG + 63) / 64)     // 1563
#define GNT ((NT + 63) / 64)     // 782

// concatenated CSR segment space: [G_lg(EG) | G_dst(NG) | T_lg(ET) | T_dst(NT)]
#define SEG1 EG
#define SEG2 (EG + NG)
#define SEG3 (EG + NG + ET)
#define NSEG_ALL (EG + NG + ET + NT)
#define NE_ALL (ELG + EG + ELGT + ET)
// padded CSR upper bound: every segment rounded up to multiple of 4
#define NE_PAD (NE_ALL + 3 * NSEG_ALL + 64)

typedef unsigned short u16;
typedef unsigned int u32;
typedef __attribute__((ext_vector_type(8))) short bf16x8;
typedef __attribute__((ext_vector_type(4))) float f32x4;
typedef __attribute__((ext_vector_type(4))) u32 u32x4;
typedef __attribute__((ext_vector_type(2))) u32 u32x2;

#define TILE_B 16384   // one 64-row x 128-col bf16 tile (row stride 256 B)

__device__ __forceinline__ float bflo(u32 p){ return __uint_as_float(p << 16); }
__device__ __forceinline__ float bfhi(u32 p){ return __uint_as_float(p & 0xffff0000u); }
__device__ __forceinline__ float bf2f(u16 h){ return __uint_as_float(((u32)h) << 16); }
__device__ __forceinline__ u16 f2bf(float f){
  u32 u = __float_as_uint(f);
  u32 r = u + 0x7fffu + ((u >> 16) & 1u);
  return (u16)(r >> 16);
}
__device__ __forceinline__ float sigm(float x){ return 1.0f / (1.0f + __expf(-x)); }
__device__ __forceinline__ float tanh_(float x){ return 2.0f / (1.0f + __expf(-2.0f * x)) - 1.0f; }
__device__ __forceinline__ float relu_(float x){ return x > 0.0f ? x : 0.0f; }
__device__ __forceinline__ void wfence(){ __builtin_amdgcn_wave_barrier(); }

// non-temporal (cache-bypass) accessors
__device__ __forceinline__ uint4 ldnt4(const void* p){
  u32x4 v = __builtin_nontemporal_load((const u32x4*)p);
  return make_uint4(v.x, v.y, v.z, v.w);
}
__device__ __forceinline__ void stnt4(void* p, uint4 d){
  u32x4 v = {d.x, d.y, d.z, d.w};
  __builtin_nontemporal_store(v, (u32x4*)p);
}
__device__ __forceinline__ uint2 ldnt2(const void* p){
  u32x2 v = __builtin_nontemporal_load((const u32x2*)p);
  return make_uint2(v.x, v.y);
}
__device__ __forceinline__ void stnt2(void* p, uint2 d){
  u32x2 v = {d.x, d.y};
  __builtin_nontemporal_store(v, (u32x2*)p);
}

// LDS tile byte swizzle (T2): row stride 256B, XOR row bits into byte bits 4-6
__device__ __forceinline__ int swz(int r, int c){ return r * 256 + (c ^ ((r & 7) << 4)); }

__device__ __forceinline__ void zero8(float v[8]){
  #pragma unroll
  for (int j = 0; j < 8; j++) v[j] = 0.f;
}
__device__ __forceinline__ uint4 pack8(const float v[8]){
  uint4 o;
  o.x = f2bf(v[0]) | ((u32)f2bf(v[1]) << 16);
  o.y = f2bf(v[2]) | ((u32)f2bf(v[3]) << 16);
  o.z = f2bf(v[4]) | ((u32)f2bf(v[5]) << 16);
  o.w = f2bf(v[6]) | ((u32)f2bf(v[7]) << 16);
  return o;
}
__device__ __forceinline__ uint2 pack4(const f32x4& a){
  uint2 o;
  o.x = (u32)f2bf(a[0]) | ((u32)f2bf(a[1]) << 16);
  o.y = (u32)f2bf(a[2]) | ((u32)f2bf(a[3]) << 16);
  return o;
}
__device__ __forceinline__ void unp4(uint2 u, float v[4]){
  v[0] = bflo(u.x); v[1] = bfhi(u.x); v[2] = bflo(u.y); v[3] = bfhi(u.y);
}
__device__ __forceinline__ uint2 pack4a(const float v[4]){
  uint2 o;
  o.x = (u32)f2bf(v[0]) | ((u32)f2bf(v[1]) << 16);
  o.y = (u32)f2bf(v[2]) | ((u32)f2bf(v[3]) << 16);
  return o;
}
__device__ __forceinline__ bf16x8 packfrag(const float v[8]){
  union { uint4 u; bf16x8 b; } c; c.u = pack8(v); return c.b;
}
__device__ __forceinline__ bf16x8 zfrag(){
  union { uint4 u; bf16x8 b; } c; c.u = make_uint4(0, 0, 0, 0); return c.b;
}

// ---------------- dtype sniffer (bf16 vs f32 inputs) ----------------
__global__ void k_sniff(const u32* __restrict__ g, int* __restrict__ flag){
  __shared__ int sh[2];
  if (threadIdx.x < 2) sh[threadIdx.x] = 0;
  __syncthreads();
  int c0 = 0, c1 = 0;
  for (int i = 0; i < 16; i++){
    u32 w = g[threadIdx.x * 16 + i];
    u32 lo = w & 0xFFFFu;
    if (lo == 0u) c0++;
    else { u32 e = (lo >> 7) & 0xFFu; if (e >= 96u && e <= 144u) c1++; }
  }
  atomicAdd(&sh[0], c0); atomicAdd(&sh[1], c1);
  __syncthreads();
  if (threadIdx.x == 0) *flag = (sh[0] < 512 && sh[1] > 2048) ? 1 : 0;
}

// all 13 weights -> f32 mirror arena (one launch)
__global__ void k_cvt_all(const void* p0, const void* p1, const void* p2, const void* p3,
                          const void* p4, const void* p5, const void* p6, const void* p7,
                          const void* p8, const void* p9, const void* p10, const void* p11,
                          const void* p12, float* __restrict__ wm, const int* __restrict__ flagp){
  int i = blockIdx.x * 256 + threadIdx.x;
  if (i >= 188416) return;
  const int offs[14] = {0,8192,16384,32768,40960,57344,73728,90112,106496,122880,139264,155648,172032,188416};
  const void* ps[13] = {p0,p1,p2,p3,p4,p5,p6,p7,p8,p9,p10,p11,p12};
  int w = 0;
  while (i >= offs[w + 1]) w++;
  int li = i - offs[w];
  wm[i] = (*flagp) ? bf2f(((const u16*)ps[w])[li]) : ((const float*)ps[w])[li];
}

// all MFMA B-fragment tables (one launch, 46 ks-blocks)
__global__ void k_mkfrag_all(const float* __restrict__ wm, u16* __restrict__ frag){
  const int wmo[13] = {0,8192,16384,32768,40960,57344,73728,90112,106496,122880,139264,155648,172032};
  const int nks[13] = {2,2,4,2,4,4,4,4,4,4,4,4,4};
  int b = blockIdx.x;            // 0..45
  int wi = 0, ks = b;
  while (ks >= nks[wi]){ ks -= nks[wi]; wi++; }
  const float* W = wm + wmo[wi];
  int nt = threadIdx.x >> 6, lane = threadIdx.x & 63;
  int kr = ks * 32 + ((lane >> 4) << 3);
  int col = nt * 16 + (lane & 15);
  u16* o = frag + (size_t)b * 4096 + nt * 512 + lane * 8;
  #pragma unroll
  for (int j = 0; j < 8; j++) o[j] = f2bf(W[(size_t)(kr + j) * 128 + col]);
}

// ---------------- dual-dtype row access ----------------
__device__ __forceinline__ const void* rowdt(const void* mat, size_t row, int W, int bf){
  return bf ? (const void*)((const u16*)mat + row * (size_t)W)
            : (const void*)((const float*)mat + row * (size_t)W);
}
__device__ __forceinline__ void load8(const void* rowbase, int c8, int bf, float v[8]){
  if (bf){
    uint4 d = ((const uint4*)rowbase)[c8];
    v[0]=bflo(d.x); v[1]=bfhi(d.x); v[2]=bflo(d.y); v[3]=bfhi(d.y);
    v[4]=bflo(d.z); v[5]=bfhi(d.z); v[6]=bflo(d.w); v[7]=bfhi(d.w);
  } else {
    const float4* p = (const float4*)rowbase + (c8 << 1);
    float4 a = p[0], b = p[1];
    v[0]=a.x; v[1]=a.y; v[2]=a.z; v[3]=a.w; v[4]=b.x; v[5]=b.y; v[6]=b.z; v[7]=b.w;
  }
}
// non-temporal variant (read-once streams)
__device__ __forceinline__ void load8_nt(const void* rowbase, int c8, int bf, float v[8]){
  if (bf){
    uint4 d = ldnt4((const uint4*)rowbase + c8);
    v[0]=bflo(d.x); v[1]=bfhi(d.x); v[2]=bflo(d.y); v[3]=bfhi(d.y);
    v[4]=bflo(d.z); v[5]=bfhi(d.z); v[6]=bflo(d.w); v[7]=bfhi(d.w);
  } else {
    uint4 a = ldnt4((const float4*)rowbase + (c8 << 1));
    uint4 b = ldnt4((const float4*)rowbase + (c8 << 1) + 1);
    v[0]=__uint_as_float(a.x); v[1]=__uint_as_float(a.y);
    v[2]=__uint_as_float(a.z); v[3]=__uint_as_float(a.w);
    v[4]=__uint_as_float(b.x); v[5]=__uint_as_float(b.y);
    v[6]=__uint_as_float(b.z); v[7]=__uint_as_float(b.w);
  }
}

// ---------------- unified CSR build (padded to multiples of 4) ----------------
__global__ void k_hist_all(const int* __restrict__ Glgd, const int* __restrict__ Gd,
                           const int* __restrict__ Tlgd, const int* __restrict__ Td,
                           int* __restrict__ cnt){
  int e = blockIdx.x * 256 + threadIdx.x;
  if (e >= NE_ALL) return;
  int seg;
  if (e < ELG)                       seg = Glgd[e];
  else if (e < ELG + EG)             seg = SEG1 + Gd[e - ELG];
  else if (e < ELG + EG + ELGT)      seg = SEG2 + Tlgd[e - ELG - EG];
  else                               seg = SEG3 + Td[e - ELG - EG - ELGT];
  atomicAdd(&cnt[seg], 1);
}

__global__ void k_scan1(const int* __restrict__ cnt, int n, int* __restrict__ csum){
  int base = blockIdx.x * 4096, tid = threadIdx.x;
  int s = 0;
  for (int i = 0; i < 16; i++){
    int idx = base + i * 256 + tid;
    if (idx < n) s += (cnt[idx] + 3) & ~3;      // padded count
  }
  __shared__ int red[4];
  for (int off = 32; off; off >>= 1) s += __shfl_down(s, off, 64);
  if ((tid & 63) == 0) red[tid >> 6] = s;
  __syncthreads();
  if (tid == 0) csum[blockIdx.x] = red[0] + red[1] + red[2] + red[3];
}

__global__ void k_scan2(int* csum, int nch, int* rowptr, int n){
  if (threadIdx.x == 0){
    int run = 0;
    for (int c = 0; c < nch; c++){ int t = csum[c]; csum[c] = run; run += t; }
    rowptr[n] = run;
  }
}

__global__ void k_scan3(const int* __restrict__ cnt, int n, const int* __restrict__ csum,
                        int* __restrict__ rowptr){
  __shared__ int buf[4096];
  __shared__ int tsum[256];
  int base = blockIdx.x * 4096, tid = threadIdx.x;
  for (int i = 0; i < 16; i++){
    int idx = base + i * 256 + tid;
    buf[i * 256 + tid] = (idx < n) ? ((cnt[idx] + 3) & ~3) : 0;   // padded count
  }
  __syncthreads();
  int run = 0;
  for (int i = 0; i < 16; i++){ int v = buf[tid * 16 + i]; buf[tid * 16 + i] = run; run += v; }
  tsum[tid] = run;
  __syncthreads();
  for (int off = 1; off < 256; off <<= 1){
    int v = (tid >= off) ? tsum[tid - off] : 0;
    __syncthreads();
    tsum[tid] += v;
    __syncthreads();
  }
  int texcl = tsum[tid] - run;
  int cbase = csum[blockIdx.x];
  for (int i = 0; i < 16; i++){
    int idx = base + tid * 16 + i;
    if (idx < n) rowptr[idx] = cbase + texcl + buf[tid * 16 + i];
  }
}

__global__ void k_fill_all(const int* __restrict__ Glgd, const int* __restrict__ Glgs,
                           const int* __restrict__ Gd,
                           const int* __restrict__ Tlgd, const int* __restrict__ Tlgs,
                           const int* __restrict__ Td,
                           const int* __restrict__ rowptr, int* __restrict__ fill,
                           int* __restrict__ col){
  int e = blockIdx.x * 256 + threadIdx.x;
  if (e >= NE_ALL) return;
  int seg, srcv;
  if (e < ELG){                      seg = Glgd[e];                           srcv = Glgs[e]; }
  else if (e < ELG + EG){            int l = e - ELG;                         seg = SEG1 + Gd[l];   srcv = l; }
  else if (e < ELG + EG + ELGT){     int l = e - ELG - EG;                    seg = SEG2 + Tlgd[l]; srcv = Tlgs[l]; }
  else {                             int l = e - ELG - EG - ELGT;             seg = SEG3 + Td[l];   srcv = l; }
  int pos = atomicAdd(&fill[seg], 1);
  col[rowptr[seg] + pos] = srcv;
}

// fill the padding tail of every segment with the dummy (zero) row index
__global__ void k_fill_pad(const int* __restrict__ cnt, const int* __restrict__ rowptr,
                           int* __restrict__ col){
  int seg = blockIdx.x * 256 + threadIdx.x;
  if (seg >= NSEG_ALL) return;
  int dummy = (seg < SEG2) ? EG : ET;          // msgG dummy row / msgT dummy row
  int start = rowptr[seg] + cnt[seg];
  int end = rowptr[seg + 1];
  for (int q = start; q < end; q++) col[q] = dummy;
}

// zero the dummy msg rows (ws is poisoned 0xAA)
__global__ void k_zero_dummy(u16* a, u16* b, u16* c, u16* d){
  int i = threadIdx.x;
  if (i < 128){
    a[(size_t)EG * 128 + i] = 0; b[(size_t)EG * 128 + i] = 0;
    c[(size_t)ET * 128 + i] = 0; d[(size_t)ET * 128 + i] = 0;
  }
}

// ---------------- register-direct gather + MFMA ----------------

__device__ __forceinline__ void acc8_add(float (&a)[8], uint4 d){
  a[0] += bflo(d.x); a[1] += bfhi(d.x);
  a[2] += bflo(d.y); a[3] += bfhi(d.y);
  a[4] += bflo(d.z); a[5] += bfhi(d.z);
  a[6] += bflo(d.w); a[7] += bfhi(d.w);
}

// CSR gather-sum (rows padded to x4, rowptr 4-aligned) of bf16 msg rows into
// A-fragment accumulators. colidx batch loaded as one uint4.
__device__ __forceinline__ void gather_accum(const int* __restrict__ rowptr,
    const int* __restrict__ colidx, const u16* __restrict__ msg,
    int row, int M, int kg, float (&acc)[4][8])
{
  #pragma unroll
  for (int ks = 0; ks < 4; ks++) zero8(acc[ks]);
  if (row >= M) return;
  int p = rowptr[row], pe = rowptr[row + 1];
  for (; p < pe; p += 4){
    uint4 ci = *(const uint4*)(colidx + p);
    const uint4* b0 = (const uint4*)(msg + (size_t)ci.x * 128);
    const uint4* b1 = (const uint4*)(msg + (size_t)ci.y * 128);
    const uint4* b2 = (const uint4*)(msg + (size_t)ci.z * 128);
    const uint4* b3 = (const uint4*)(msg + (size_t)ci.w * 128);
    uint4 v0[4], v1[4], v2[4], v3[4];
    #pragma unroll
    for (int ks = 0; ks < 4; ks++){
      v0[ks] = b0[ks * 4 + kg]; v1[ks] = b1[ks * 4 + kg];
      v2[ks] = b2[ks * 4 + kg]; v3[ks] = b3[ks * 4 + kg];
    }
    #pragma unroll
    for (int ks = 0; ks < 4; ks++){
      acc8_add(acc[ks], v0[ks]); acc8_add(acc[ks], v1[ks]);
      acc8_add(acc[ks], v2[ks]); acc8_add(acc[ks], v3[ks]);
    }
  }
}

// acc[nt] += A(frags in regs) @ Wfrag, KS ksteps
template<int KS>
__device__ __forceinline__ void mma_f(const bf16x8* a, const u16* __restrict__ frag,
                                      f32x4 (&acc)[8])
{
  int lane = threadIdx.x & 63;
  #pragma unroll
  for (int ks = 0; ks < KS; ks++){
    const u16* fb = frag + (size_t)ks * 4096 + lane * 8;
    #pragma unroll
    for (int nt = 0; nt < 8; nt++){
      bf16x8 b = *(const bf16x8*)(fb + (size_t)nt * 512);
      acc[nt] = __builtin_amdgcn_mfma_f32_16x16x32_bf16(a[ks], b, acc[nt], 0, 0, 0);
    }
  }
}

#define INIT_ACC(A) { _Pragma("unroll") for (int n_=0;n_<8;n_++){ A[n_][0]=0.f; A[n_][1]=0.f; A[n_][2]=0.f; A[n_][3]=0.f; } }

// tile (bf16, swizzled, wave-stripe-local) -> row-major global bf16 (nt store)
__device__ __forceinline__ void repack_store(const char* __restrict__ tile,
    u16* __restrict__ dst, int row0, int M)
{
  int rl = threadIdx.x >> 2, q = threadIdx.x & 3;
  int grow = row0 + rl;
  if (grow < M){
    #pragma unroll
    for (int v = 0; v < 4; v++){
      uint4 d = *(const uint4*)(tile + swz(rl, (v * 4 + q) * 16));
      stnt4(dst + (size_t)grow * 128 + (size_t)(v * 4 + q) * 8, d);
    }
  }
}

// frag-major uint2 slot: [blk][w][nt][lane][4 bf16]
__device__ __forceinline__ size_t fslot(int blk, int w, int nt){
  return ((((size_t)blk * 4 + w) * 8 + nt) * 64 + (threadIdx.x & 63)) * 4;
}

// load the 4 A-fragments of concat(Gf[Gsrc[arow]], Gef[arow]) for this lane
// Gf: cached (13 MB, random-reused); Gef: non-temporal (read-once stream)
__device__ __forceinline__ void load_catfrag(const void* __restrict__ Gf,
    const void* __restrict__ Gef, const int* __restrict__ Gsrc,
    int arow, int kg, int bf, bf16x8 (&fC)[4])
{
  if (arow < EG){
    int sr = Gsrc[arow];
    const void* ra = rowdt(Gf, (size_t)sr, 64, bf);
    const void* rb = rowdt(Gef, (size_t)arow, 64, bf);
    float t[8];
    load8(ra, kg, bf, t);        fC[0] = packfrag(t);
    load8(ra, 4 + kg, bf, t);    fC[1] = packfrag(t);
    load8_nt(rb, kg, bf, t);     fC[2] = packfrag(t);
    load8_nt(rb, 4 + kg, bf, t); fC[3] = packfrag(t);
  } else {
    #pragma unroll
    for (int ks = 0; ks < 4; ks++) fC[ks] = zfrag();
  }
}

// ---------------- merged pipeline kernels (single 16 KB tile everywhere) ----------------

// blocks [0,GET): xz/xr/xh = emb[Tid[Tsrc]]@{Wz,Wr,Wh}; msgT = sig(xz)*tanh(xh)
// blocks [GET,GET+GEG): msgG = relu(Gf[Gsrc]@W1 + Gef@W2)
__global__ __launch_bounds__(256, 4) void k_init(
    const void* __restrict__ Gf, const void* __restrict__ Gef, const int* __restrict__ Gsrc,
    const u16* __restrict__ fWcat, const int* __restrict__ flagp, u16* __restrict__ msgG,
    const void* __restrict__ emb, const int* __restrict__ Tid, const int* __restrict__ Tsrc,
    const u16* __restrict__ fWz, const u16* __restrict__ fWr, const u16* __restrict__ fWh,
    u16* __restrict__ xzf, u16* __restrict__ xrf, u16* __restrict__ xhf, u16* __restrict__ msgT)
{
  __shared__ char t0[TILE_B];
  int bf = *flagp;
  int lane = threadIdx.x & 63, w = threadIdx.x >> 6;
  int stripe = w * 16, kg = lane >> 4, m16 = lane & 15;
  if (blockIdx.x < GET){
    int blk = blockIdx.x, row0 = blk * 64, arow = row0 + stripe + m16;
    bf16x8 fE[4];
    if (arow < ET){
      int id = Tid[Tsrc[arow]];
      const void* rb = rowdt(emb, (size_t)id, 128, bf);
      #pragma unroll
      for (int ks = 0; ks < 4; ks++){
        float t[8]; load8(rb, ks * 4 + kg, bf, t); fE[ks] = packfrag(t);
      }
    } else {
      #pragma unroll
      for (int ks = 0; ks < 4; ks++) fE[ks] = zfrag();
    }
    f32x4 acc[8];
    uint2 zpk[8];
    INIT_ACC(acc);
    mma_f<4>(fE, fWz, acc);                       // aZ
    #pragma unroll
    for (int nt = 0; nt < 8; nt++){
      zpk[nt] = pack4(acc[nt]);
      stnt2(xzf + fslot(blk, w, nt), zpk[nt]);
    }
    INIT_ACC(acc);
    mma_f<4>(fE, fWr, acc);                       // aR
    #pragma unroll
    for (int nt = 0; nt < 8; nt++)
      stnt2(xrf + fslot(blk, w, nt), pack4(acc[nt]));
    INIT_ACC(acc);
    mma_f<4>(fE, fWh, acc);                       // aH
    #pragma unroll
    for (int nt = 0; nt < 8; nt++){
      stnt2(xhf + fslot(blk, w, nt), pack4(acc[nt]));
      float xzv[4]; unp4(zpk[nt], xzv);
      #pragma unroll
      for (int r = 0; r < 4; r++){
        int rt = stripe + (kg << 2) + r;
        int cb = nt * 32 + m16 * 2;
        *(u16*)(t0 + swz(rt, cb)) = f2bf(sigm(xzv[r]) * tanh_(acc[nt][r]));
      }
    }
    wfence();
    repack_store(t0, msgT, row0, ET);
  } else {
    int blk = blockIdx.x - GET, row0 = blk * 64, arow = row0 + stripe + m16;
    bf16x8 fC[4];
    load_catfrag(Gf, Gef, Gsrc, arow, kg, bf, fC);
    f32x4 acc[8]; INIT_ACC(acc);
    mma_f<4>(fC, fWcat, acc);
    #pragma unroll
    for (int nt = 0; nt < 8; nt++)
      #pragma unroll
      for (int r = 0; r < 4; r++){
        int rt = stripe + (kg << 2) + r;
        int cb = nt * 32 + m16 * 2;
        *(u16*)(t0 + swz(rt, cb)) = f2bf(relu_(acc[nt][r]));
      }
    wfence();
    repack_store(t0, msgG, row0, EG);
  }
}

// blocks [0,GET): T GRU iter — single tile; S kept in regs (spk) + fS frags in regs
// blocks [GET,GET+GEG): G iter — gather-first, base recomputed in regs
__global__ __launch_bounds__(256, 4) void k_iter(
    const u16* __restrict__ msgInG, u16* __restrict__ msgOutG,
    const void* __restrict__ Gf, const void* __restrict__ Gef, const int* __restrict__ Gsrc,
    const int* __restrict__ rp, const int* __restrict__ col,
    const u16* __restrict__ fWcat, const u16* __restrict__ fW3, const int* __restrict__ flagp,
    const u16* __restrict__ msgInT, u16* __restrict__ msgOutT,
    const u16* __restrict__ fUz, const u16* __restrict__ fUr, const u16* __restrict__ fUh,
    const u16* __restrict__ xzf, const u16* __restrict__ xrf, const u16* __restrict__ xhf)
{
  __shared__ char t0[TILE_B];
  int lane = threadIdx.x & 63, w = threadIdx.x >> 6;
  int stripe = w * 16, kg = lane >> 4, m16 = lane & 15;
  if (blockIdx.x < GET){
    // ---- T GRU step (single 16 KB tile) ----
    int blk = blockIdx.x, row0 = blk * 64, arow = row0 + stripe + m16;
    float ga[4][8];
    gather_accum(rp + SEG2, col, msgInT, arow, ET, kg, ga);
    bf16x8 fS[4];
    #pragma unroll
    for (int ks = 0; ks < 4; ks++){
      uint4 pk = pack8(ga[ks]);
      *(uint4*)(t0 + swz(stripe + m16, ks * 64 + kg * 16)) = pk;  // S tile (A-layout)
      fS[ks] = *(bf16x8*)&pk;
    }
    wfence();
    // pull S at C-positions into regs, freeing the tile
    uint2 spk[8];
    #pragma unroll
    for (int nt = 0; nt < 8; nt++){
      float sv[4];
      #pragma unroll
      for (int r = 0; r < 4; r++){
        int rt = stripe + (kg << 2) + r;
        int cb = nt * 32 + m16 * 2;
        sv[r] = bf2f(*(const u16*)(t0 + swz(rt, cb)));
      }
      spk[nt] = pack4a(sv);
    }
    f32x4 acc[8];
    INIT_ACC(acc);
    mma_f<4>(fS, fUr, acc);                      // S@Ur
    wfence();
    #pragma unroll
    for (int nt = 0; nt < 8; nt++){
      uint2 xr4 = ldnt2(xrf + fslot(blk, w, nt));
      float xrv[4], sv[4];
      unp4(xr4, xrv); unp4(spk[nt], sv);
      #pragma unroll
      for (int r = 0; r < 4; r++){
        int rt = stripe + (kg << 2) + r;
        int cb = nt * 32 + m16 * 2;
        float rr = sigm(xrv[r] + acc[nt][r]);
        *(u16*)(t0 + swz(rt, cb)) = f2bf(rr * sv[r]);   // r*s tile (C-positions)
      }
    }
    // z = sigm(xz + S@Uz) while the tile settles (fS still in regs)
    INIT_ACC(acc);
    mma_f<4>(fS, fUz, acc);
    uint2 zpk[8];
    #pragma unroll
    for (int nt = 0; nt < 8; nt++){
      uint2 xz4 = ldnt2(xzf + fslot(blk, w, nt));
      float xzv[4], zv[4];
      unp4(xz4, xzv);
      #pragma unroll
      for (int r = 0; r < 4; r++) zv[r] = sigm(xzv[r] + acc[nt][r]);
      zpk[nt] = pack4a(zv);
    }
    wfence();
    bf16x8 fRS[4];
    #pragma unroll
    for (int ks = 0; ks < 4; ks++)
      fRS[ks] = *(const bf16x8*)(t0 + swz(stripe + m16, ks * 64 + kg * 16));
    INIT_ACC(acc);
    mma_f<4>(fRS, fUh, acc);                     // (r*s)@Uh
    wfence();
    #pragma unroll
    for (int nt = 0; nt < 8; nt++){
      uint2 xh4 = ldnt2(xhf + fslot(blk, w, nt));
      float xhv[4], sv[4], zv[4];
      unp4(xh4, xhv); unp4(spk[nt], sv); unp4(zpk[nt], zv);
      #pragma unroll
      for (int r = 0; r < 4; r++){
        int rt = stripe + (kg << 2) + r;
        int cb = nt * 32 + m16 * 2;
        float h = tanh_(xhv[r] + acc[nt][r]);
        *(u16*)(t0 + swz(rt, cb)) = f2bf((1.f - zv[r]) * sv[r] + zv[r] * h);
      }
    }
    wfence();
    repack_store(t0, msgOutT, row0, ET);
  } else {
    // ---- G iter: msgOut = relu(Gf[Gsrc]@W1 + Gef@W2 + segsum(msgIn)@W3) ----
    int bf = *flagp;
    int blk = blockIdx.x - GET, row0 = blk * 64, arow = row0 + stripe + m16;
    float ga[4][8];
    gather_accum(rp, col, msgInG, arow, EG, kg, ga);
    bf16x8 fS[4];
    #pragma unroll
    for (int ks = 0; ks < 4; ks++) fS[ks] = packfrag(ga[ks]);
    bf16x8 fC[4];
    load_catfrag(Gf, Gef, Gsrc, arow, kg, bf, fC);   // latency hides under fS@W3 mma
    f32x4 acc[8]; INIT_ACC(acc);
    mma_f<4>(fS, fW3, acc);
    mma_f<4>(fC, fWcat, acc);
    #pragma unroll
    for (int nt = 0; nt < 8; nt++)
      #pragma unroll
      for (int r = 0; r < 4; r++){
        int rt = stripe + (kg << 2) + r;
        int cb = nt * 32 + m16 * 2;
        *(u16*)(t0 + swz(rt, cb)) = f2bf(relu_(acc[nt][r]));
      }
    wfence();
    repack_store(t0, msgOutG, row0, EG);
  }
}

// blocks [0,GNT): out_T = relu(emb[Tid]@U1T + segsum(msgT)@U2T)
// blocks [GNT,GNT+GNG): out_G = relu(Gf@U1G + segsum(msgG)@U2G)   (LDS-free)
__global__ __launch_bounds__(256, 4) void k_readout(
    const void* __restrict__ Gf, const u16* __restrict__ msgG,
    const int* __restrict__ rp, const int* __restrict__ col,
    const u16* __restrict__ fU1G, const u16* __restrict__ fU2G,
    const void* __restrict__ emb, const int* __restrict__ Tid, const u16* __restrict__ msgT,
    const u16* __restrict__ fU1T, const u16* __restrict__ fU2T,
    const int* __restrict__ flagp, float* __restrict__ out)
{
  int bf = *flagp;
  int lane = threadIdx.x & 63, w = threadIdx.x >> 6;
  int stripe = w * 16, kg = lane >> 4, m16 = lane & 15;
  if (blockIdx.x < GNT){
    int row0 = blockIdx.x * 64, arow = row0 + stripe + m16;
    float ga[4][8];
    gather_accum(rp + SEG3, col, msgT, arow, NT, kg, ga);
    bf16x8 fS[4];
    #pragma unroll
    for (int ks = 0; ks < 4; ks++) fS[ks] = packfrag(ga[ks]);
    bf16x8 fE[4];
    if (arow < NT){
      int id = Tid[arow];
      const void* rb = rowdt(emb, (size_t)id, 128, bf);
      #pragma unroll
      for (int ks = 0; ks < 4; ks++){
        float t[8]; load8(rb, ks * 4 + kg, bf, t); fE[ks] = packfrag(t);
      }
    } else {
      #pragma unroll
      for (int ks = 0; ks < 4; ks++) fE[ks] = zfrag();
    }
    f32x4 acc[8]; INIT_ACC(acc);
    mma_f<4>(fS, fU2T, acc);
    mma_f<4>(fE, fU1T, acc);
    #pragma unroll
    for (int nt = 0; nt < 8; nt++)
      #pragma unroll
      for (int r = 0; r < 4; r++){
        int R = row0 + stripe + (kg << 2) + r;
        if (R < NT) __builtin_nontemporal_store(relu_(acc[nt][r]),
                        &out[(size_t)(NG + R) * 128 + nt * 16 + m16]);
      }
  } else {
    int row0 = (blockIdx.x - GNT) * 64, arow = row0 + stripe + m16;
    float ga[4][8];
    gather_accum(rp + SEG1, col, msgG, arow, NG, kg, ga);
    bf16x8 fS[4];
    #pragma unroll
    for (int ks = 0; ks < 4; ks++) fS[ks] = packfrag(ga[ks]);
    bf16x8 fG[2];
    if (arow < NG){
      const void* ra = rowdt(Gf, (size_t)arow, 64, bf);
      float t[8];
      load8_nt(ra, kg, bf, t);     fG[0] = packfrag(t);
      load8_nt(ra, 4 + kg, bf, t); fG[1] = packfrag(t);
    } else { fG[0] = zfrag(); fG[1] = zfrag(); }
    f32x4 acc[8]; INIT_ACC(acc);
    mma_f<4>(fS, fU2G, acc);
    mma_f<2>(fG, fU1G, acc);
    #pragma unroll
    for (int nt = 0; nt < 8; nt++)
      #pragma unroll
      for (int r = 0; r < 4; r++){
        int R = row0 + stripe + (kg << 2) + r;
        if (R < NG) __builtin_nontemporal_store(relu_(acc[nt][r]),
                        &out[(size_t)R * 128 + nt * 16 + m16]);
      }
  }
}

// ---------------- host launcher ----------------
extern "C" void kernel_launch(void* const* d_in, const int* in_sizes, int n_in,
                              void* d_out, int out_size, void* d_ws, size_t ws_size,
                              hipStream_t stream)
{
  const void* G_f      = d_in[0];
  const void* G_ef     = d_in[1];
  const int*  G_src    = (const int*)d_in[2];
  const int*  G_dst    = (const int*)d_in[3];
  const int*  G_lg_src = (const int*)d_in[4];
  const int*  G_lg_dst = (const int*)d_in[5];
  const int*  T_id     = (const int*)d_in[6];
  const int*  T_src    = (const int*)d_in[7];
  const int*  T_dst    = (const int*)d_in[8];
  const int*  T_lg_src = (const int*)d_in[9];
  const int*  T_lg_dst = (const int*)d_in[10];
  const void* emb      = d_in[11];
  float* out = (float*)d_out;
  (void)in_sizes; (void)n_in; (void)out_size; (void)ws_size;

  size_t off = 0;
  auto alloc = [&](size_t bytes) -> char* {
    char* p = (char*)d_ws + off;
    off += (bytes + 255) & ~(size_t)255;
    return p;
  };

  int*   flag = (int*)alloc(256);
  float* wm   = (float*)alloc(sizeof(float) * 188416);
  u16*   frag = (u16*)alloc(2 * 46 * 4096);
  const u16* fWcat = frag;
  const u16* fW3   = frag + (size_t)4  * 4096;
  const u16* fU1G  = frag + (size_t)8  * 4096;
  const u16* fU2G  = frag + (size_t)10 * 4096;
  const u16* fWz   = frag + (size_t)14 * 4096;
  const u16* fUz   = frag + (size_t)18 * 4096;
  const u16* fWr   = frag + (size_t)22 * 4096;
  const u16* fUr   = frag + (size_t)26 * 4096;
  const u16* fWh   = frag + (size_t)30 * 4096;
  const u16* fUh   = frag + (size_t)34 * 4096;
  const u16* fU1T  = frag + (size_t)38 * 4096;
  const u16* fU2T  = frag + (size_t)42 * 4096;

  int* rp   = (int*)alloc(sizeof(int) * (NSEG_ALL + 1));
  int* col  = (int*)alloc(sizeof(int) * NE_PAD);
  int* cnt  = (int*)alloc(sizeof(int) * 2 * NSEG_ALL);
  int* csum = (int*)alloc(sizeof(int) * 256);
  u16* msgGA = (u16*)alloc((size_t)(EG + 1) * 128 * 2);
  u16* msgGB = (u16*)alloc((size_t)(EG + 1) * 128 * 2);
  u16* xzf   = (u16*)alloc((size_t)GET * 8192 * 2);
  u16* xrf   = (u16*)alloc((size_t)GET * 8192 * 2);
  u16* xhf   = (u16*)alloc((size_t)GET * 8192 * 2);
  u16* msgTA = (u16*)alloc((size_t)(ET + 1) * 128 * 2);
  u16* msgTB = (u16*)alloc((size_t)(ET + 1) * 128 * 2);
  // total ws ≈ 360 MB (r8 footprint)

  // setup: dtype flag -> weight mirrors -> fragment tables
  k_sniff<<<1, 256, 0, stream>>>((const u32*)G_ef, flag);
  k_cvt_all<<<(188416 + 255) / 256, 256, 0, stream>>>(
      d_in[12], d_in[13], d_in[14], d_in[15], d_in[16], d_in[17], d_in[18],
      d_in[19], d_in[20], d_in[21], d_in[22], d_in[23], d_in[24], wm, flag);
  k_mkfrag_all<<<46, 512, 0, stream>>>(wm, frag);
  k_zero_dummy<<<1, 128, 0, stream>>>(msgGA, msgGB, msgTA, msgTB);

  // unified padded CSR build
  hipMemsetAsync(cnt, 0, sizeof(int) * 2 * NSEG_ALL, stream);
  k_hist_all<<<(NE_ALL + 255) / 256, 256, 0, stream>>>(G_lg_dst, G_dst, T_lg_dst, T_dst, cnt);
  int nch = (NSEG_ALL + 4095) / 4096;
  k_scan1<<<nch, 256, 0, stream>>>(cnt, NSEG_ALL, csum);
  k_scan2<<<1, 64, 0, stream>>>(csum, nch, rp, NSEG_ALL);
  k_scan3<<<nch, 256, 0, stream>>>(cnt, NSEG_ALL, csum, rp);
  k_fill_all<<<(NE_ALL + 255) / 256, 256, 0, stream>>>(
      G_lg_dst, G_lg_src, G_dst, T_lg_dst, T_lg_src, T_dst, rp, cnt + NSEG_ALL, col);
  k_fill_pad<<<(NSEG_ALL + 255) / 256, 256, 0, stream>>>(cnt, rp, col);

  // merged pipeline (5 launches, T blocks first)
  k_init<<<GET + GEG, 256, 0, stream>>>(G_f, G_ef, G_src, fWcat, flag, msgGA,
                                        emb, T_id, T_src, fWz, fWr, fWh, xzf, xrf, xhf, msgTA);
  k_iter<<<GET + GEG, 256, 0, stream>>>(msgGA, msgGB, G_f, G_ef, G_src, rp, col, fWcat, fW3, flag,
                                        msgTA, msgTB, fUz, fUr, fUh, xzf, xrf, xhf);
  k_iter<<<GET + GEG, 256, 0, stream>>>(msgGB, msgGA, G_f, G_ef, G_src, rp, col, fWcat, fW3, flag,
                                        msgTB, msgTA, fUz, fUr, fUh, xzf, xrf, xhf);
  k_iter<<<GET + GEG, 256, 0, stream>>>(msgGA, msgGB, G_f, G_ef, G_src, rp, col, fWcat, fW3, flag,
                                        msgTA, msgTB, fUz, fUr, fUh, xzf, xrf, xhf);
  k_readout<<<GNT + GNG, 256, 0, stream>>>(G_f, msgGB, rp, col, fU1G, fU2G,
                                           emb, T_id, msgTB, fU1T, fU2T, flag, out);
}

// Round 13
// 1094.382 us; speedup vs baseline: 2.7813x; 1.1409x over previous
//
#include <hip/hip_runtime.h>

#define NG 100000
#define EG 400000
#define ELG 1200000
#define NT 50000
#define ET 100000
#define ELGT 300000

#define GEG ((EG + 63) / 64)     // 6250
#define GET ((ET + 63) / 64)     // 1563
#define GNG ((NG + 63) / 64)     // 1563
#define GNT ((NT + 63) / 64)     // 782

// concatenated CSR segment space: [G_lg(EG) | G_dst(NG) | T_lg(ET) | T_dst(NT)]
#define SEG1 EG
#define SEG2 (EG + NG)
#define SEG3 (EG + NG + ET)
#define NSEG_ALL (EG + NG + ET + NT)
#define NE_ALL (ELG + EG + ELGT + ET)
// padded CSR upper bound: every segment rounded up to multiple of 4
#define NE_PAD (NE_ALL + 3 * NSEG_ALL + 64)

// fused-kernel block layout
#define HISTB ((NE_ALL + 511) / 512)          // 3907 hist blocks (512 thr)
#define FILLB ((NE_ALL + 255) / 256)          // 7813 fill blocks (256 thr)
#define PADB  ((NSEG_ALL + 255) / 256)        // 2540 pad blocks

typedef unsigned short u16;
typedef unsigned int u32;
typedef __attribute__((ext_vector_type(8))) short bf16x8;
typedef __attribute__((ext_vector_type(4))) float f32x4;
typedef __attribute__((ext_vector_type(4))) u32 u32x4;
typedef __attribute__((ext_vector_type(2))) u32 u32x2;

#define TILE_B 16384   // one 64-row x 128-col bf16 tile (row stride 256 B)

__device__ __forceinline__ float bflo(u32 p){ return __uint_as_float(p << 16); }
__device__ __forceinline__ float bfhi(u32 p){ return __uint_as_float(p & 0xffff0000u); }
__device__ __forceinline__ float bf2f(u16 h){ return __uint_as_float(((u32)h) << 16); }
__device__ __forceinline__ u16 f2bf(float f){
  u32 u = __float_as_uint(f);
  u32 r = u + 0x7fffu + ((u >> 16) & 1u);
  return (u16)(r >> 16);
}
__device__ __forceinline__ float sigm(float x){ return 1.0f / (1.0f + __expf(-x)); }
__device__ __forceinline__ float tanh_(float x){ return 2.0f / (1.0f + __expf(-2.0f * x)) - 1.0f; }
__device__ __forceinline__ float relu_(float x){ return x > 0.0f ? x : 0.0f; }
__device__ __forceinline__ void wfence(){ __builtin_amdgcn_wave_barrier(); }

// non-temporal (cache-bypass) accessors
__device__ __forceinline__ uint4 ldnt4(const void* p){
  u32x4 v = __builtin_nontemporal_load((const u32x4*)p);
  return make_uint4(v.x, v.y, v.z, v.w);
}
__device__ __forceinline__ void stnt4(void* p, uint4 d){
  u32x4 v = {d.x, d.y, d.z, d.w};
  __builtin_nontemporal_store(v, (u32x4*)p);
}
__device__ __forceinline__ uint2 ldnt2(const void* p){
  u32x2 v = __builtin_nontemporal_load((const u32x2*)p);
  return make_uint2(v.x, v.y);
}
__device__ __forceinline__ void stnt2(void* p, uint2 d){
  u32x2 v = {d.x, d.y};
  __builtin_nontemporal_store(v, (u32x2*)p);
}

// LDS tile byte swizzle (T2): row stride 256B, XOR row bits into byte bits 4-6
__device__ __forceinline__ int swz(int r, int c){ return r * 256 + (c ^ ((r & 7) << 4)); }

__device__ __forceinline__ void zero8(float v[8]){
  #pragma unroll
  for (int j = 0; j < 8; j++) v[j] = 0.f;
}
__device__ __forceinline__ uint4 pack8(const float v[8]){
  uint4 o;
  o.x = f2bf(v[0]) | ((u32)f2bf(v[1]) << 16);
  o.y = f2bf(v[2]) | ((u32)f2bf(v[3]) << 16);
  o.z = f2bf(v[4]) | ((u32)f2bf(v[5]) << 16);
  o.w = f2bf(v[6]) | ((u32)f2bf(v[7]) << 16);
  return o;
}
__device__ __forceinline__ uint2 pack4(const f32x4& a){
  uint2 o;
  o.x = (u32)f2bf(a[0]) | ((u32)f2bf(a[1]) << 16);
  o.y = (u32)f2bf(a[2]) | ((u32)f2bf(a[3]) << 16);
  return o;
}
__device__ __forceinline__ void unp4(uint2 u, float v[4]){
  v[0] = bflo(u.x); v[1] = bfhi(u.x); v[2] = bflo(u.y); v[3] = bfhi(u.y);
}
__device__ __forceinline__ bf16x8 packfrag(const float v[8]){
  union { uint4 u; bf16x8 b; } c; c.u = pack8(v); return c.b;
}
__device__ __forceinline__ bf16x8 zfrag(){
  union { uint4 u; bf16x8 b; } c; c.u = make_uint4(0, 0, 0, 0); return c.b;
}
__device__ __forceinline__ bf16x8 as_frag(uint4 u){
  union { uint4 u; bf16x8 b; } c; c.u = u; return c.b;
}

// ---------------- dtype sniffer (bf16 vs f32 inputs) ----------------
__global__ void k_sniff(const u32* __restrict__ g, int* __restrict__ flag){
  __shared__ int sh[2];
  if (threadIdx.x < 2) sh[threadIdx.x] = 0;
  __syncthreads();
  int c0 = 0, c1 = 0;
  for (int i = 0; i < 16; i++){
    u32 w = g[threadIdx.x * 16 + i];
    u32 lo = w & 0xFFFFu;
    if (lo == 0u) c0++;
    else { u32 e = (lo >> 7) & 0xFFu; if (e >= 96u && e <= 144u) c1++; }
  }
  atomicAdd(&sh[0], c0); atomicAdd(&sh[1], c1);
  __syncthreads();
  if (threadIdx.x == 0) *flag = (sh[0] < 512 && sh[1] > 2048) ? 1 : 0;
}

// ---------------- dual-dtype element access ----------------
__device__ __forceinline__ float eldt(const void* mat, size_t idx, int bf){
  return bf ? bf2f(((const u16*)mat)[idx]) : ((const float*)mat)[idx];
}
__device__ __forceinline__ const void* rowdt(const void* mat, size_t row, int W, int bf){
  return bf ? (const void*)((const u16*)mat + row * (size_t)W)
            : (const void*)((const float*)mat + row * (size_t)W);
}
__device__ __forceinline__ void load8(const void* rowbase, int c8, int bf, float v[8]){
  if (bf){
    uint4 d = ((const uint4*)rowbase)[c8];
    v[0]=bflo(d.x); v[1]=bfhi(d.x); v[2]=bflo(d.y); v[3]=bfhi(d.y);
    v[4]=bflo(d.z); v[5]=bfhi(d.z); v[6]=bflo(d.w); v[7]=bfhi(d.w);
  } else {
    const float4* p = (const float4*)rowbase + (c8 << 1);
    float4 a = p[0], b = p[1];
    v[0]=a.x; v[1]=a.y; v[2]=a.z; v[3]=a.w; v[4]=b.x; v[5]=b.y; v[6]=b.z; v[7]=b.w;
  }
}
// non-temporal variant (read-once streams)
__device__ __forceinline__ void load8_nt(const void* rowbase, int c8, int bf, float v[8]){
  if (bf){
    uint4 d = ldnt4((const uint4*)rowbase + c8);
    v[0]=bflo(d.x); v[1]=bfhi(d.x); v[2]=bflo(d.y); v[3]=bfhi(d.y);
    v[4]=bflo(d.z); v[5]=bfhi(d.z); v[6]=bflo(d.w); v[7]=bfhi(d.w);
  } else {
    uint4 a = ldnt4((const float4*)rowbase + (c8 << 1));
    uint4 b = ldnt4((const float4*)rowbase + (c8 << 1) + 1);
    v[0]=__uint_as_float(a.x); v[1]=__uint_as_float(a.y);
    v[2]=__uint_as_float(a.z); v[3]=__uint_as_float(a.w);
    v[4]=__uint_as_float(b.x); v[5]=__uint_as_float(b.y);
    v[6]=__uint_as_float(b.z); v[7]=__uint_as_float(b.w);
  }
}

// ---------------- fused setup: mkfrag (46) | zero_dummy (1) | hist (HISTB) ----------------
// mkfrag reads the ORIGINAL dual-dtype weights (no f32 mirror pass needed)
__global__ __launch_bounds__(512) void k_setup(
    const void* p0, const void* p1, const void* p2, const void* p3, const void* p4,
    const void* p5, const void* p6, const void* p7, const void* p8, const void* p9,
    const void* p10, const void* p11, const void* p12,
    u16* __restrict__ frag, const int* __restrict__ flagp,
    u16* __restrict__ mA, u16* __restrict__ mB, u16* __restrict__ mC, u16* __restrict__ mD,
    const int* __restrict__ Glgd, const int* __restrict__ Gd,
    const int* __restrict__ Tlgd, const int* __restrict__ Td,
    int* __restrict__ cnt)
{
  int b = blockIdx.x;
  if (b < 46){
    // ---- B-fragment tables ----
    const int nks[13] = {2,2,4,2,4,4,4,4,4,4,4,4,4};
    const void* ps[13] = {p0,p1,p2,p3,p4,p5,p6,p7,p8,p9,p10,p11,p12};
    int bf = *flagp;
    int wi = 0, ks = b;
    while (ks >= nks[wi]){ ks -= nks[wi]; wi++; }
    const void* W = ps[wi];
    int nt = threadIdx.x >> 6, lane = threadIdx.x & 63;
    int kr = ks * 32 + ((lane >> 4) << 3);
    int col = nt * 16 + (lane & 15);
    u16* o = frag + (size_t)b * 4096 + nt * 512 + lane * 8;
    #pragma unroll
    for (int j = 0; j < 8; j++)
      o[j] = f2bf(eldt(W, (size_t)(kr + j) * 128 + col, bf));
  } else if (b == 46){
    // ---- zero the dummy msg rows ----
    int i = threadIdx.x;
    if (i < 128){
      mA[(size_t)EG * 128 + i] = 0; mB[(size_t)EG * 128 + i] = 0;
      mC[(size_t)ET * 128 + i] = 0; mD[(size_t)ET * 128 + i] = 0;
    }
  } else {
    // ---- histogram ----
    int e = (b - 47) * 512 + threadIdx.x;
    if (e >= NE_ALL) return;
    int seg;
    if (e < ELG)                       seg = Glgd[e];
    else if (e < ELG + EG)             seg = SEG1 + Gd[e - ELG];
    else if (e < ELG + EG + ELGT)      seg = SEG2 + Tlgd[e - ELG - EG];
    else                               seg = SEG3 + Td[e - ELG - EG - ELGT];
    atomicAdd(&cnt[seg], 1);
  }
}

// ---------------- scans (padded to multiples of 4) ----------------
__global__ void k_scan1(const int* __restrict__ cnt, int n, int* __restrict__ csum){
  int base = blockIdx.x * 4096, tid = threadIdx.x;
  int s = 0;
  for (int i = 0; i < 16; i++){
    int idx = base + i * 256 + tid;
    if (idx < n) s += (cnt[idx] + 3) & ~3;      // padded count
  }
  __shared__ int red[4];
  for (int off = 32; off; off >>= 1) s += __shfl_down(s, off, 64);
  if ((tid & 63) == 0) red[tid >> 6] = s;
  __syncthreads();
  if (tid == 0) csum[blockIdx.x] = red[0] + red[1] + red[2] + red[3];
}

__global__ void k_scan2(int* csum, int nch, int* rowptr, int n){
  if (threadIdx.x == 0){
    int run = 0;
    for (int c = 0; c < nch; c++){ int t = csum[c]; csum[c] = run; run += t; }
    rowptr[n] = run;
  }
}

__global__ void k_scan3(const int* __restrict__ cnt, int n, const int* __restrict__ csum,
                        int* __restrict__ rowptr){
  __shared__ int buf[4096];
  __shared__ int tsum[256];
  int base = blockIdx.x * 4096, tid = threadIdx.x;
  for (int i = 0; i < 16; i++){
    int idx = base + i * 256 + tid;
    buf[i * 256 + tid] = (idx < n) ? ((cnt[idx] + 3) & ~3) : 0;   // padded count
  }
  __syncthreads();
  int run = 0;
  for (int i = 0; i < 16; i++){ int v = buf[tid * 16 + i]; buf[tid * 16 + i] = run; run += v; }
  tsum[tid] = run;
  __syncthreads();
  for (int off = 1; off < 256; off <<= 1){
    int v = (tid >= off) ? tsum[tid - off] : 0;
    __syncthreads();
    tsum[tid] += v;
    __syncthreads();
  }
  int texcl = tsum[tid] - run;
  int cbase = csum[blockIdx.x];
  for (int i = 0; i < 16; i++){
    int idx = base + tid * 16 + i;
    if (idx < n) rowptr[idx] = cbase + texcl + buf[tid * 16 + i];
  }
}

// ---------------- register-direct gather + MFMA ----------------

__device__ __forceinline__ void acc8_add(float (&a)[8], uint4 d){
  a[0] += bflo(d.x); a[1] += bfhi(d.x);
  a[2] += bflo(d.y); a[3] += bfhi(d.y);
  a[4] += bflo(d.z); a[5] += bfhi(d.z);
  a[6] += bflo(d.w); a[7] += bfhi(d.w);
}

// CSR gather-sum (rows padded to x4, rowptr 4-aligned) of bf16 msg rows into
// A-fragment accumulators. colidx batch loaded as one uint4.
__device__ __forceinline__ void gather_accum(const int* __restrict__ rowptr,
    const int* __restrict__ colidx, const u16* __restrict__ msg,
    int row, int M, int kg, float (&acc)[4][8])
{
  #pragma unroll
  for (int ks = 0; ks < 4; ks++) zero8(acc[ks]);
  if (row >= M) return;
  int p = rowptr[row], pe = rowptr[row + 1];
  for (; p < pe; p += 4){
    uint4 ci = *(const uint4*)(colidx + p);
    const uint4* b0 = (const uint4*)(msg + (size_t)ci.x * 128);
    const uint4* b1 = (const uint4*)(msg + (size_t)ci.y * 128);
    const uint4* b2 = (const uint4*)(msg + (size_t)ci.z * 128);
    const uint4* b3 = (const uint4*)(msg + (size_t)ci.w * 128);
    uint4 v0[4], v1[4], v2[4], v3[4];
    #pragma unroll
    for (int ks = 0; ks < 4; ks++){
      v0[ks] = b0[ks * 4 + kg]; v1[ks] = b1[ks * 4 + kg];
      v2[ks] = b2[ks * 4 + kg]; v3[ks] = b3[ks * 4 + kg];
    }
    #pragma unroll
    for (int ks = 0; ks < 4; ks++){
      acc8_add(acc[ks], v0[ks]); acc8_add(acc[ks], v1[ks]);
      acc8_add(acc[ks], v2[ks]); acc8_add(acc[ks], v3[ks]);
    }
  }
}

// acc[nt] += A(frags in regs) @ Wfrag, KS ksteps
template<int KS>
__device__ __forceinline__ void mma_f(const bf16x8* a, const u16* __restrict__ frag,
                                      f32x4 (&acc)[8])
{
  int lane = threadIdx.x & 63;
  #pragma unroll
  for (int ks = 0; ks < KS; ks++){
    const u16* fb = frag + (size_t)ks * 4096 + lane * 8;
    #pragma unroll
    for (int nt = 0; nt < 8; nt++){
      bf16x8 b = *(const bf16x8*)(fb + (size_t)nt * 512);
      acc[nt] = __builtin_amdgcn_mfma_f32_16x16x32_bf16(a[ks], b, acc[nt], 0, 0, 0);
    }
  }
}

#define INIT_ACC(A) { _Pragma("unroll") for (int n_=0;n_<8;n_++){ A[n_][0]=0.f; A[n_][1]=0.f; A[n_][2]=0.f; A[n_][3]=0.f; } }

// tile (bf16, swizzled, wave-stripe-local) -> row-major global bf16 (nt store)
__device__ __forceinline__ void repack_store(const char* __restrict__ tile,
    u16* __restrict__ dst, int row0, int M)
{
  int rl = threadIdx.x >> 2, q = threadIdx.x & 3;
  int grow = row0 + rl;
  if (grow < M){
    #pragma unroll
    for (int v = 0; v < 4; v++){
      uint4 d = *(const uint4*)(tile + swz(rl, (v * 4 + q) * 16));
      stnt4(dst + (size_t)grow * 128 + (size_t)(v * 4 + q) * 8, d);
    }
  }
}

// frag-major uint2 slot: [blk][w][nt][lane][4 bf16]
__device__ __forceinline__ size_t fslot(int blk, int w, int nt){
  return ((((size_t)blk * 4 + w) * 8 + nt) * 64 + (threadIdx.x & 63)) * 4;
}

// load the 4 A-fragments of concat(Gf[Gsrc[arow]], Gef[arow]) for this lane
// Gf: cached (13 MB, random-reused); Gef: non-temporal (read-once stream)
__device__ __forceinline__ void load_catfrag(const void* __restrict__ Gf,
    const void* __restrict__ Gef, const int* __restrict__ Gsrc,
    int arow, int kg, int bf, bf16x8 (&fC)[4])
{
  if (arow < EG){
    int sr = Gsrc[arow];
    const void* ra = rowdt(Gf, (size_t)sr, 64, bf);
    const void* rb = rowdt(Gef, (size_t)arow, 64, bf);
    float t[8];
    load8(ra, kg, bf, t);        fC[0] = packfrag(t);
    load8(ra, 4 + kg, bf, t);    fC[1] = packfrag(t);
    load8_nt(rb, kg, bf, t);     fC[2] = packfrag(t);
    load8_nt(rb, 4 + kg, bf, t); fC[3] = packfrag(t);
  } else {
    #pragma unroll
    for (int ks = 0; ks < 4; ks++) fC[ks] = zfrag();
  }
}

// ---------------- k_init device body (shared by fused kernel) ----------------
__device__ __forceinline__ void init_body(int idx,
    const void* __restrict__ Gf, const void* __restrict__ Gef, const int* __restrict__ Gsrc,
    const u16* __restrict__ fWcat, int bf, u16* __restrict__ msgG,
    const void* __restrict__ emb, const int* __restrict__ Tid, const int* __restrict__ Tsrc,
    const u16* __restrict__ fWz, const u16* __restrict__ fWr, const u16* __restrict__ fWh,
    u16* __restrict__ xzf, u16* __restrict__ xrf, u16* __restrict__ xhf, u16* __restrict__ msgT,
    char* t0)
{
  int lane = threadIdx.x & 63, w = threadIdx.x >> 6;
  int stripe = w * 16, kg = lane >> 4, m16 = lane & 15;
  if (idx < GET){
    int blk = idx, row0 = blk * 64, arow = row0 + stripe + m16;
    bf16x8 fE[4];
    if (arow < ET){
      int id = Tid[Tsrc[arow]];
      const void* rb = rowdt(emb, (size_t)id, 128, bf);
      #pragma unroll
      for (int ks = 0; ks < 4; ks++){
        float t[8]; load8(rb, ks * 4 + kg, bf, t); fE[ks] = packfrag(t);
      }
    } else {
      #pragma unroll
      for (int ks = 0; ks < 4; ks++) fE[ks] = zfrag();
    }
    f32x4 acc[8];
    uint2 zpk[8];
    INIT_ACC(acc);
    mma_f<4>(fE, fWz, acc);                       // aZ
    #pragma unroll
    for (int nt = 0; nt < 8; nt++){
      zpk[nt] = pack4(acc[nt]);
      stnt2(xzf + fslot(blk, w, nt), zpk[nt]);
    }
    INIT_ACC(acc);
    mma_f<4>(fE, fWr, acc);                       // aR
    #pragma unroll
    for (int nt = 0; nt < 8; nt++)
      stnt2(xrf + fslot(blk, w, nt), pack4(acc[nt]));
    INIT_ACC(acc);
    mma_f<4>(fE, fWh, acc);                       // aH
    #pragma unroll
    for (int nt = 0; nt < 8; nt++){
      stnt2(xhf + fslot(blk, w, nt), pack4(acc[nt]));
      float xzv[4]; unp4(zpk[nt], xzv);
      #pragma unroll
      for (int r = 0; r < 4; r++){
        int rt = stripe + (kg << 2) + r;
        int cb = nt * 32 + m16 * 2;
        *(u16*)(t0 + swz(rt, cb)) = f2bf(sigm(xzv[r]) * tanh_(acc[nt][r]));
      }
    }
    wfence();
    repack_store(t0, msgT, row0, ET);
  } else {
    int blk = idx - GET, row0 = blk * 64, arow = row0 + stripe + m16;
    bf16x8 fC[4];
    load_catfrag(Gf, Gef, Gsrc, arow, kg, bf, fC);
    f32x4 acc[8]; INIT_ACC(acc);
    mma_f<4>(fC, fWcat, acc);
    #pragma unroll
    for (int nt = 0; nt < 8; nt++)
      #pragma unroll
      for (int r = 0; r < 4; r++){
        int rt = stripe + (kg << 2) + r;
        int cb = nt * 32 + m16 * 2;
        *(u16*)(t0 + swz(rt, cb)) = f2bf(relu_(acc[nt][r]));
      }
    wfence();
    repack_store(t0, msgG, row0, EG);
  }
}

// ---------------- fused: fill_all | fill_pad | k_init ----------------
__global__ __launch_bounds__(256, 4) void k_fill_init(
    const int* __restrict__ Glgd, const int* __restrict__ Glgs, const int* __restrict__ Gd,
    const int* __restrict__ Tlgd, const int* __restrict__ Tlgs, const int* __restrict__ Td,
    const int* __restrict__ rowptr, int* __restrict__ fill, int* __restrict__ col,
    const int* __restrict__ cnt,
    const void* __restrict__ Gf, const void* __restrict__ Gef, const int* __restrict__ Gsrc,
    const u16* __restrict__ fWcat, const int* __restrict__ flagp, u16* __restrict__ msgG,
    const void* __restrict__ emb, const int* __restrict__ Tid, const int* __restrict__ Tsrc,
    const u16* __restrict__ fWz, const u16* __restrict__ fWr, const u16* __restrict__ fWh,
    u16* __restrict__ xzf, u16* __restrict__ xrf, u16* __restrict__ xhf, u16* __restrict__ msgT)
{
  __shared__ char t0[TILE_B];
  int b = blockIdx.x;
  if (b < FILLB){
    // ---- CSR fill ----
    int e = b * 256 + threadIdx.x;
    if (e >= NE_ALL) return;
    int seg, srcv;
    if (e < ELG){                      seg = Glgd[e];                           srcv = Glgs[e]; }
    else if (e < ELG + EG){            int l = e - ELG;                         seg = SEG1 + Gd[l];   srcv = l; }
    else if (e < ELG + EG + ELGT){     int l = e - ELG - EG;                    seg = SEG2 + Tlgd[l]; srcv = Tlgs[l]; }
    else {                             int l = e - ELG - EG - ELGT;             seg = SEG3 + Td[l];   srcv = l; }
    int pos = atomicAdd(&fill[seg], 1);
    col[rowptr[seg] + pos] = srcv;
  } else if (b < FILLB + PADB){
    // ---- padding tail -> dummy row ----
    int seg = (b - FILLB) * 256 + threadIdx.x;
    if (seg >= NSEG_ALL) return;
    int dummy = (seg < SEG2) ? EG : ET;
    int start = rowptr[seg] + cnt[seg];
    int end = rowptr[seg + 1];
    for (int q = start; q < end; q++) col[q] = dummy;
  } else {
    // ---- k_init body ----
    init_body(b - FILLB - PADB, Gf, Gef, Gsrc, fWcat, *flagp, msgG,
              emb, Tid, Tsrc, fWz, fWr, fWh, xzf, xrf, xhf, msgT, t0);
  }
}

// ---------------- merged iter kernel (r8-identical hot path) ----------------
// blocks [0,GET): T GRU iter; blocks [GET,GET+GEG): G iter
__global__ __launch_bounds__(256, 4) void k_iter(
    const u16* __restrict__ msgInG, u16* __restrict__ msgOutG,
    const void* __restrict__ Gf, const void* __restrict__ Gef, const int* __restrict__ Gsrc,
    const int* __restrict__ rp, const int* __restrict__ col,
    const u16* __restrict__ fWcat, const u16* __restrict__ fW3, const int* __restrict__ flagp,
    const u16* __restrict__ msgInT, u16* __restrict__ msgOutT,
    const u16* __restrict__ fUz, const u16* __restrict__ fUr, const u16* __restrict__ fUh,
    const u16* __restrict__ xzf, const u16* __restrict__ xrf, const u16* __restrict__ xhf)
{
  __shared__ char t0[TILE_B];
  __shared__ char t1[TILE_B];
  int lane = threadIdx.x & 63, w = threadIdx.x >> 6;
  int stripe = w * 16, kg = lane >> 4, m16 = lane & 15;
  if (blockIdx.x < GET){
    // ---- T GRU step ----
    int blk = blockIdx.x, row0 = blk * 64, arow = row0 + stripe + m16;
    float ga[4][8];
    gather_accum(rp + SEG2, col, msgInT, arow, ET, kg, ga);
    bf16x8 fS[4];
    #pragma unroll
    for (int ks = 0; ks < 4; ks++){
      uint4 pk = pack8(ga[ks]);
      *(uint4*)(t0 + swz(stripe + m16, ks * 64 + kg * 16)) = pk;  // S tile
      fS[ks] = as_frag(pk);
    }
    f32x4 acc[8];
    INIT_ACC(acc);
    mma_f<4>(fS, fUr, acc);                      // aR
    wfence();
    #pragma unroll
    for (int nt = 0; nt < 8; nt++){
      uint2 r4 = ldnt2(xrf + fslot(blk, w, nt));
      float xrv[4]; unp4(r4, xrv);
      #pragma unroll
      for (int r = 0; r < 4; r++){
        int rt = stripe + (kg << 2) + r;
        int cb = nt * 32 + m16 * 2;
        float s = bf2f(*(const u16*)(t0 + swz(rt, cb)));
        float rr = sigm(xrv[r] + acc[nt][r]);
        *(u16*)(t1 + swz(rt, cb)) = f2bf(rr * s);   // r*s tile
      }
    }
    wfence();
    bf16x8 fRS[4];
    #pragma unroll
    for (int ks = 0; ks < 4; ks++)
      fRS[ks] = *(const bf16x8*)(t1 + swz(stripe + m16, ks * 64 + kg * 16));
    INIT_ACC(acc);
    mma_f<4>(fRS, fUh, acc);                     // aH
    wfence();
    #pragma unroll
    for (int nt = 0; nt < 8; nt++){
      uint2 h4 = ldnt2(xhf + fslot(blk, w, nt));
      float xhv[4]; unp4(h4, xhv);
      #pragma unroll
      for (int r = 0; r < 4; r++){
        int rt = stripe + (kg << 2) + r;
        int cb = nt * 32 + m16 * 2;
        *(u16*)(t1 + swz(rt, cb)) = f2bf(tanh_(xhv[r] + acc[nt][r]));   // h tile
      }
    }
    wfence();
    bf16x8 fS2[4];
    #pragma unroll
    for (int ks = 0; ks < 4; ks++)
      fS2[ks] = *(const bf16x8*)(t0 + swz(stripe + m16, ks * 64 + kg * 16));
    INIT_ACC(acc);
    mma_f<4>(fS2, fUz, acc);                     // aZ
    wfence();
    #pragma unroll
    for (int nt = 0; nt < 8; nt++){
      uint2 z4 = ldnt2(xzf + fslot(blk, w, nt));
      float xzv[4]; unp4(z4, xzv);
      #pragma unroll
      for (int r = 0; r < 4; r++){
        int rt = stripe + (kg << 2) + r;
        int cb = nt * 32 + m16 * 2;
        float z = sigm(xzv[r] + acc[nt][r]);
        float s = bf2f(*(const u16*)(t0 + swz(rt, cb)));
        float h = bf2f(*(const u16*)(t1 + swz(rt, cb)));
        *(u16*)(t0 + swz(rt, cb)) = f2bf((1.f - z) * s + z * h);
      }
    }
    wfence();
    repack_store(t0, msgOutT, row0, ET);
  } else {
    // ---- G iter: msgOut = relu(Gf[Gsrc]@W1 + Gef@W2 + segsum(msgIn)@W3) ----
    int bf = *flagp;
    int blk = blockIdx.x - GET, row0 = blk * 64, arow = row0 + stripe + m16;
    float ga[4][8];
    gather_accum(rp, col, msgInG, arow, EG, kg, ga);
    bf16x8 fS[4];
    #pragma unroll
    for (int ks = 0; ks < 4; ks++) fS[ks] = packfrag(ga[ks]);
    bf16x8 fC[4];
    load_catfrag(Gf, Gef, Gsrc, arow, kg, bf, fC);   // latency hides under fS@W3 mma
    f32x4 acc[8]; INIT_ACC(acc);
    mma_f<4>(fS, fW3, acc);
    mma_f<4>(fC, fWcat, acc);
    #pragma unroll
    for (int nt = 0; nt < 8; nt++)
      #pragma unroll
      for (int r = 0; r < 4; r++){
        int rt = stripe + (kg << 2) + r;
        int cb = nt * 32 + m16 * 2;
        *(u16*)(t0 + swz(rt, cb)) = f2bf(relu_(acc[nt][r]));
      }
    wfence();
    repack_store(t0, msgOutG, row0, EG);
  }
}

// blocks [0,GNT): out_T = relu(emb[Tid]@U1T + segsum(msgT)@U2T)
// blocks [GNT,GNT+GNG): out_G = relu(Gf@U1G + segsum(msgG)@U2G)   (LDS-free)
__global__ __launch_bounds__(256, 4) void k_readout(
    const void* __restrict__ Gf, const u16* __restrict__ msgG,
    const int* __restrict__ rp, const int* __restrict__ col,
    const u16* __restrict__ fU1G, const u16* __restrict__ fU2G,
    const void* __restrict__ emb, const int* __restrict__ Tid, const u16* __restrict__ msgT,
    const u16* __restrict__ fU1T, const u16* __restrict__ fU2T,
    const int* __restrict__ flagp, float* __restrict__ out)
{
  int bf = *flagp;
  int lane = threadIdx.x & 63, w = threadIdx.x >> 6;
  int stripe = w * 16, kg = lane >> 4, m16 = lane & 15;
  if (blockIdx.x < GNT){
    int row0 = blockIdx.x * 64, arow = row0 + stripe + m16;
    float ga[4][8];
    gather_accum(rp + SEG3, col, msgT, arow, NT, kg, ga);
    bf16x8 fS[4];
    #pragma unroll
    for (int ks = 0; ks < 4; ks++) fS[ks] = packfrag(ga[ks]);
    bf16x8 fE[4];
    if (arow < NT){
      int id = Tid[arow];
      const void* rb = rowdt(emb, (size_t)id, 128, bf);
      #pragma unroll
      for (int ks = 0; ks < 4; ks++){
        float t[8]; load8(rb, ks * 4 + kg, bf, t); fE[ks] = packfrag(t);
      }
    } else {
      #pragma unroll
      for (int ks = 0; ks < 4; ks++) fE[ks] = zfrag();
    }
    f32x4 acc[8]; INIT_ACC(acc);
    mma_f<4>(fS, fU2T, acc);
    mma_f<4>(fE, fU1T, acc);
    #pragma unroll
    for (int nt = 0; nt < 8; nt++)
      #pragma unroll
      for (int r = 0; r < 4; r++){
        int R = row0 + stripe + (kg << 2) + r;
        if (R < NT) __builtin_nontemporal_store(relu_(acc[nt][r]),
                        &out[(size_t)(NG + R) * 128 + nt * 16 + m16]);
      }
  } else {
    int row0 = (blockIdx.x - GNT) * 64, arow = row0 + stripe + m16;
    float ga[4][8];
    gather_accum(rp + SEG1, col, msgG, arow, NG, kg, ga);
    bf16x8 fS[4];
    #pragma unroll
    for (int ks = 0; ks < 4; ks++) fS[ks] = packfrag(ga[ks]);
    bf16x8 fG[2];
    if (arow < NG){
      const void* ra = rowdt(Gf, (size_t)arow, 64, bf);
      float t[8];
      load8_nt(ra, kg, bf, t);     fG[0] = packfrag(t);
      load8_nt(ra, 4 + kg, bf, t); fG[1] = packfrag(t);
    } else { fG[0] = zfrag(); fG[1] = zfrag(); }
    f32x4 acc[8]; INIT_ACC(acc);
    mma_f<4>(fS, fU2G, acc);
    mma_f<2>(fG, fU1G, acc);
    #pragma unroll
    for (int nt = 0; nt < 8; nt++)
      #pragma unroll
      for (int r = 0; r < 4; r++){
        int R = row0 + stripe + (kg << 2) + r;
        if (R < NG) __builtin_nontemporal_store(relu_(acc[nt][r]),
                        &out[(size_t)R * 128 + nt * 16 + m16]);
      }
  }
}

// ---------------- host launcher ----------------
extern "C" void kernel_launch(void* const* d_in, const int* in_sizes, int n_in,
                              void* d_out, int out_size, void* d_ws, size_t ws_size,
                              hipStream_t stream)
{
  const void* G_f      = d_in[0];
  const void* G_ef     = d_in[1];
  const int*  G_src    = (const int*)d_in[2];
  const int*  G_dst    = (const int*)d_in[3];
  const int*  G_lg_src = (const int*)d_in[4];
  const int*  G_lg_dst = (const int*)d_in[5];
  const int*  T_id     = (const int*)d_in[6];
  const int*  T_src    = (const int*)d_in[7];
  const int*  T_dst    = (const int*)d_in[8];
  const int*  T_lg_src = (const int*)d_in[9];
  const int*  T_lg_dst = (const int*)d_in[10];
  const void* emb      = d_in[11];
  float* out = (float*)d_out;
  (void)in_sizes; (void)n_in; (void)out_size; (void)ws_size;

  size_t off = 0;
  auto alloc = [&](size_t bytes) -> char* {
    char* p = (char*)d_ws + off;
    off += (bytes + 255) & ~(size_t)255;
    return p;
  };

  int*   flag = (int*)alloc(256);
  u16*   frag = (u16*)alloc(2 * 46 * 4096);
  const u16* fWcat = frag;
  const u16* fW3   = frag + (size_t)4  * 4096;
  const u16* fU1G  = frag + (size_t)8  * 4096;
  const u16* fU2G  = frag + (size_t)10 * 4096;
  const u16* fWz   = frag + (size_t)14 * 4096;
  const u16* fUz   = frag + (size_t)18 * 4096;
  const u16* fWr   = frag + (size_t)22 * 4096;
  const u16* fUr   = frag + (size_t)26 * 4096;
  const u16* fWh   = frag + (size_t)30 * 4096;
  const u16* fUh   = frag + (size_t)34 * 4096;
  const u16* fU1T  = frag + (size_t)38 * 4096;
  const u16* fU2T  = frag + (size_t)42 * 4096;

  int* rp   = (int*)alloc(sizeof(int) * (NSEG_ALL + 1));
  int* col  = (int*)alloc(sizeof(int) * NE_PAD);
  int* cnt  = (int*)alloc(sizeof(int) * 2 * NSEG_ALL);
  int* csum = (int*)alloc(sizeof(int) * 256);
  u16* msgGA = (u16*)alloc((size_t)(EG + 1) * 128 * 2);
  u16* msgGB = (u16*)alloc((size_t)(EG + 1) * 128 * 2);
  u16* xzf   = (u16*)alloc((size_t)GET * 8192 * 2);
  u16* xrf   = (u16*)alloc((size_t)GET * 8192 * 2);
  u16* xhf   = (u16*)alloc((size_t)GET * 8192 * 2);
  u16* msgTA = (u16*)alloc((size_t)(ET + 1) * 128 * 2);
  u16* msgTB = (u16*)alloc((size_t)(ET + 1) * 128 * 2);
  // total ws ≈ 360 MB (r8 footprint minus the f32 weight mirror)

  // memset fill counters first (needed by hist in k_setup), then sniff -> setup
  hipMemsetAsync(cnt, 0, sizeof(int) * 2 * NSEG_ALL, stream);
  k_sniff<<<1, 256, 0, stream>>>((const u32*)G_ef, flag);
  k_setup<<<47 + HISTB, 512, 0, stream>>>(
      d_in[12], d_in[13], d_in[14], d_in[15], d_in[16], d_in[17], d_in[18],
      d_in[19], d_in[20], d_in[21], d_in[22], d_in[23], d_in[24],
      frag, flag, msgGA, msgGB, msgTA, msgTB,
      G_lg_dst, G_dst, T_lg_dst, T_dst, cnt);

  int nch = (NSEG_ALL + 4095) / 4096;
  k_scan1<<<nch, 256, 0, stream>>>(cnt, NSEG_ALL, csum);
  k_scan2<<<1, 64, 0, stream>>>(csum, nch, rp, NSEG_ALL);
  k_scan3<<<nch, 256, 0, stream>>>(cnt, NSEG_ALL, csum, rp);

  // fused: CSR fill + padding + k_init (one launch)
  k_fill_init<<<FILLB + PADB + GET + GEG, 256, 0, stream>>>(
      G_lg_dst, G_lg_src, G_dst, T_lg_dst, T_lg_src, T_dst,
      rp, cnt + NSEG_ALL, col, cnt,
      G_f, G_ef, G_src, fWcat, flag, msgGA,
      emb, T_id, T_src, fWz, fWr, fWh, xzf, xrf, xhf, msgTA);

  // 3 message-passing iterations (merged T+G)
  k_iter<<<GET + GEG, 256, 0, stream>>>(msgGA, msgGB, G_f, G_ef, G_src, rp, col, fWcat, fW3, flag,
                                        msgTA, msgTB, fUz, fUr, fUh, xzf, xrf, xhf);
  k_iter<<<GET + GEG, 256, 0, stream>>>(msgGB, msgGA, G_f, G_ef, G_src, rp, col, fWcat, fW3, flag,
                                        msgTB, msgTA, fUz, fUr, fUh, xzf, xrf, xhf);
  k_iter<<<GET + GEG, 256, 0, stream>>>(msgGA, msgGB, G_f, G_ef, G_src, rp, col, fWcat, fW3, flag,
                                        msgTA, msgTB, fUz, fUr, fUh, xzf, xrf, xhf);
  k_readout<<<GNT + GNG, 256, 0, stream>>>(G_f, msgGB, rp, col, fU1G, fU2G,
                                           emb, T_id, msgTB, fU1T, fU2T, flag, out);
}